// Round 1
// baseline (400.255 us; speedup 1.0000x reference)
//
#include <hip/hip_runtime.h>
#include <hip/hip_bf16.h>

// Problem constants
#define B_   2
#define S_   2048
#define DIM_ 2048
#define NH   16
#define NKV  4
#define HD   128

typedef __attribute__((ext_vector_type(8))) short  sv8;   // 8 x bf16 (MFMA operand)
typedef __attribute__((ext_vector_type(8))) ushort usv8;
typedef __attribute__((ext_vector_type(4))) float  fv4;

__device__ __forceinline__ ushort f2bf(float f) {
  __hip_bfloat16 h = __float2bfloat16(f);
  union { __hip_bfloat16 h; ushort u; } c; c.h = h; return c.u;
}
__device__ __forceinline__ float bf2f(ushort u) {
  union { unsigned int i; float f; } c; c.i = ((unsigned)u) << 16; return c.f;
}

// async global->LDS, 16B per lane; l must be wave-uniform, g is per-lane.
__device__ __forceinline__ void async16(const void* g, void* l) {
  __builtin_amdgcn_global_load_lds(
      (const __attribute__((address_space(1))) unsigned int*)g,
      (__attribute__((address_space(3))) unsigned int*)l, 16, 0, 0);
}

// ---------------- f32 -> bf16 convert ----------------
__global__ void cvt_kernel(const float* __restrict__ in, ushort* __restrict__ out, int n) {
  int i = (blockIdx.x * 256 + threadIdx.x) * 4;
  if (i >= n) return;
  fv4 v = *(const fv4*)(in + i);
  ushort4 o;
  o.x = f2bf(v[0]); o.y = f2bf(v[1]); o.z = f2bf(v[2]); o.w = f2bf(v[3]);
  *(ushort4*)(out + i) = o;
}

// ---------------- RoPE (+ optional scale), relayout to (B, heads, S, HD) ----------------
__global__ void rope_kernel(const ushort* __restrict__ raw, const float* __restrict__ fc,
                            const float* __restrict__ fs, ushort* __restrict__ out,
                            int heads, float scale) {
  int t = blockIdx.x * 256 + threadIdx.x;   // B*S*heads*16 threads, 8 elems each
  int grp = t & 15;
  int h   = (t >> 4) % heads;
  int s   = ((t >> 4) / heads) % S_;
  int b   = t / (16 * heads * S_);
  const ushort* src = raw + ((size_t)(b * S_ + s) * heads + h) * HD + grp * 8;
  sv8 v = *(const sv8*)src;
  fv4 c  = *(const fv4*)(fc + s * 64 + grp * 4);
  fv4 sn = *(const fv4*)(fs + s * 64 + grp * 4);
  sv8 o;
#pragma unroll
  for (int p = 0; p < 4; ++p) {
    float re = bf2f((ushort)v[2 * p]);
    float im = bf2f((ushort)v[2 * p + 1]);
    float orr = (re * c[p] - im * sn[p]) * scale;
    float oi  = (re * sn[p] + im * c[p]) * scale;
    o[2 * p]     = (short)f2bf(orr);
    o[2 * p + 1] = (short)f2bf(oi);
  }
  ushort* dst = out + ((size_t)(b * heads + h) * S_ + s) * HD + grp * 8;
  *(sv8*)dst = o;
}

// ---------------- V transpose: (B,S,KVH,HD) -> (B,KVH,HD,S) ----------------
__global__ __launch_bounds__(256) void vtrans_kernel(const ushort* __restrict__ vraw,
                                                     ushort* __restrict__ vt) {
  __shared__ ushort tile[128][136];
  int blk = blockIdx.x;            // (b*NKV+kv)*16 + st
  int st  = blk & 15;
  int kvb = blk >> 4;
  int kv  = kvb & 3;
  int b   = kvb >> 2;
  int s0  = st << 7;
#pragma unroll
  for (int it = 0; it < 8; ++it) {
    int t = it * 256 + threadIdx.x;
    int srow = t >> 4;
    int d8 = (t & 15) * 8;
    usv8 v = *(const usv8*)(vraw + (size_t)(b * S_ + s0 + srow) * (NKV * HD) + kv * HD + d8);
#pragma unroll
    for (int j = 0; j < 8; ++j) tile[d8 + j][srow] = v[j];
  }
  __syncthreads();
#pragma unroll
  for (int it = 0; it < 8; ++it) {
    int t = it * 256 + threadIdx.x;
    int d = t >> 4;
    int s8 = (t & 15) * 8;
    usv8 o;
#pragma unroll
    for (int j = 0; j < 8; ++j) o[j] = tile[d][s8 + j];
    *(usv8*)(vt + ((size_t)(b * NKV + kv) * HD + d) * S_ + s0 + s8) = o;
  }
}

// ---------------- GEMM: C[M,N] = A[M,K] * B[N,K]^T  (bf16 in, OutT out) ----------------
// 128x128 tile, BK=64, 4 waves (2x2 of 64x64), global_load_lds staging, XOR-swizzled LDS.
template <typename OutT>
__global__ __launch_bounds__(256) void gemm_bt(const ushort* __restrict__ A,
                                               const ushort* __restrict__ Bm,
                                               OutT* __restrict__ C,
                                               int M, int N, int K) {
  __shared__ ushort As[128 * 64];
  __shared__ ushort Bs[128 * 64];
  int nb = N >> 7;
  int bx = blockIdx.x % nb;
  int by = blockIdx.x / nb;
  int m0 = by << 7, n0 = bx << 7;
  int lane = threadIdx.x & 63, w = threadIdx.x >> 6;
  int l15 = lane & 15, lg = lane >> 4;
  int wm = (w >> 1) * 64, wn = (w & 1) * 64;

  const ushort* aSrc[4]; const ushort* bSrc[4];
  ushort* aDst[4]; ushort* bDst[4];
#pragma unroll
  for (int it = 0; it < 4; ++it) {
    int lin = it * 4096 + w * 1024 + lane * 16;   // byte offset into 16KB tile
    int row = lin >> 7;                           // 128B rows
    int cb  = (lin & 127) ^ ((row & 7) << 4);     // inverse swizzle on source col
    aSrc[it] = A  + (size_t)(m0 + row) * K + (cb >> 1);
    bSrc[it] = Bm + (size_t)(n0 + row) * K + (cb >> 1);
    aDst[it] = As + ((it * 4096 + w * 1024) >> 1);
    bDst[it] = Bs + ((it * 4096 + w * 1024) >> 1);
  }

  fv4 acc[4][4] = {};

  for (int kt = 0; kt < K; kt += 64) {
#pragma unroll
    for (int it = 0; it < 4; ++it) async16(aSrc[it] + kt, aDst[it]);
#pragma unroll
    for (int it = 0; it < 4; ++it) async16(bSrc[it] + kt, bDst[it]);
    __syncthreads();
#pragma unroll
    for (int kk = 0; kk < 2; ++kk) {
      sv8 af[4], bfr[4];
#pragma unroll
      for (int i = 0; i < 4; ++i) {
        int row = wm + i * 16 + l15;
        int byt = row * 128 + ((kk * 64 + (lg << 4)) ^ ((row & 7) << 4));
        af[i] = *(const sv8*)((const char*)As + byt);
      }
#pragma unroll
      for (int j = 0; j < 4; ++j) {
        int row = wn + j * 16 + l15;
        int byt = row * 128 + ((kk * 64 + (lg << 4)) ^ ((row & 7) << 4));
        bfr[j] = *(const sv8*)((const char*)Bs + byt);
      }
#pragma unroll
      for (int i = 0; i < 4; ++i)
#pragma unroll
        for (int j = 0; j < 4; ++j)
          acc[i][j] = __builtin_amdgcn_mfma_f32_16x16x32_bf16(af[i], bfr[j], acc[i][j], 0, 0, 0);
    }
    __syncthreads();
  }

#pragma unroll
  for (int i = 0; i < 4; ++i)
#pragma unroll
    for (int j = 0; j < 4; ++j)
#pragma unroll
      for (int r = 0; r < 4; ++r) {
        int row = m0 + wm + i * 16 + (lg << 2) + r;
        int col = n0 + wn + j * 16 + l15;
        if constexpr (sizeof(OutT) == 2) C[(size_t)row * N + col] = (OutT)f2bf(acc[i][j][r]);
        else                             C[(size_t)row * N + col] = (OutT)acc[i][j][r];
      }
}

// ---------------- Flash attention (causal, GQA) ----------------
// Block: 128 q-rows of one (b,h). 4 waves x 32 rows. KV tiles of 64.
__global__ __launch_bounds__(256) void attn_kernel(const ushort* __restrict__ Q,
                                                   const ushort* __restrict__ Kr,
                                                   const ushort* __restrict__ Vt,
                                                   ushort* __restrict__ O) {
  __shared__ ushort Ks[64 * 128];   // [kpos][d], 256B rows, swizzled
  __shared__ ushort Vs[128 * 64];   // [d][kpos], 128B rows, swizzled
  __shared__ ushort Ps[4][32 * 64]; // per-wave P, 128B rows, swizzled

  int blk = blockIdx.x;
  int qt = blk & 15;
  int h  = (blk >> 4) & 15;
  int b  = blk >> 8;
  int kv = h >> 2;
  int q0 = qt << 7;
  int lane = threadIdx.x & 63, w = threadIdx.x >> 6;
  int l15 = lane & 15, lg = lane >> 4;
  int qrow_base = q0 + w * 32;

  const ushort* Qbase = Q  + (size_t)(b * NH  + h ) * S_ * HD;
  const ushort* Kbase = Kr + (size_t)(b * NKV + kv) * S_ * HD;
  const ushort* Vbase = Vt + (size_t)(b * NKV + kv) * HD * S_;

  sv8 qf[2][4];
#pragma unroll
  for (int mi = 0; mi < 2; ++mi)
#pragma unroll
    for (int kk = 0; kk < 4; ++kk)
      qf[mi][kk] = *(const sv8*)(Qbase + (size_t)(qrow_base + mi * 16 + l15) * HD + kk * 32 + lg * 8);

  const ushort* kSrc[4]; ushort* kDst[4];
  const ushort* vSrc[4]; ushort* vDst[4];
#pragma unroll
  for (int it = 0; it < 4; ++it) {
    int lin = it * 4096 + w * 1024 + lane * 16;
    { int row = lin >> 8; int cb = (lin & 255) ^ ((row & 7) << 4);
      kSrc[it] = Kbase + (size_t)row * HD + (cb >> 1);
      kDst[it] = Ks + ((it * 4096 + w * 1024) >> 1); }
    { int row = lin >> 7; int cb = (lin & 127) ^ ((row & 7) << 4);
      vSrc[it] = Vbase + (size_t)row * S_ + (cb >> 1);
      vDst[it] = Vs + ((it * 4096 + w * 1024) >> 1); }
  }

  fv4 oacc[2][8] = {};
  fv4 mrun[2], lrun[2];
#pragma unroll
  for (int mi = 0; mi < 2; ++mi)
#pragma unroll
    for (int r = 0; r < 4; ++r) { mrun[mi][r] = -1e30f; lrun[mi][r] = 0.f; }

  int nkt = (q0 >> 6) + 2;
  for (int kt = 0; kt < nkt; ++kt) {
    int k0 = kt << 6;
#pragma unroll
    for (int it = 0; it < 4; ++it) async16(kSrc[it] + (size_t)k0 * HD, kDst[it]);
#pragma unroll
    for (int it = 0; it < 4; ++it) async16(vSrc[it] + k0, vDst[it]);
    __syncthreads();

    // S = Q K^T
    fv4 sacc[2][4] = {};
#pragma unroll
    for (int kk = 0; kk < 4; ++kk) {
#pragma unroll
      for (int ni = 0; ni < 4; ++ni) {
        int row = ni * 16 + l15;
        int byt = row * 256 + ((kk * 64 + (lg << 4)) ^ ((row & 7) << 4));
        sv8 kf = *(const sv8*)((const char*)Ks + byt);
#pragma unroll
        for (int mi = 0; mi < 2; ++mi)
          sacc[mi][ni] = __builtin_amdgcn_mfma_f32_16x16x32_bf16(qf[mi][kk], kf, sacc[mi][ni], 0, 0, 0);
      }
    }

    // causal mask on diagonal tiles
    if (k0 + 63 > q0) {
#pragma unroll
      for (int mi = 0; mi < 2; ++mi)
#pragma unroll
        for (int ni = 0; ni < 4; ++ni)
#pragma unroll
          for (int r = 0; r < 4; ++r) {
            int qrow = qrow_base + mi * 16 + (lg << 2) + r;
            int kcol = k0 + ni * 16 + l15;
            if (kcol > qrow) sacc[mi][ni][r] = -1e30f;
          }
    }

    // online softmax
#pragma unroll
    for (int mi = 0; mi < 2; ++mi) {
      fv4 tmax = sacc[mi][0];
#pragma unroll
      for (int ni = 1; ni < 4; ++ni)
#pragma unroll
        for (int r = 0; r < 4; ++r) tmax[r] = fmaxf(tmax[r], sacc[mi][ni][r]);
#pragma unroll
      for (int msk = 1; msk < 16; msk <<= 1)
#pragma unroll
        for (int r = 0; r < 4; ++r) tmax[r] = fmaxf(tmax[r], __shfl_xor(tmax[r], msk, 64));
      fv4 mnew, esc, psum;
#pragma unroll
      for (int r = 0; r < 4; ++r) {
        mnew[r] = fmaxf(mrun[mi][r], tmax[r]);
        esc[r]  = __expf(mrun[mi][r] - mnew[r]);
        psum[r] = 0.f;
      }
#pragma unroll
      for (int ni = 0; ni < 4; ++ni)
#pragma unroll
        for (int r = 0; r < 4; ++r) {
          float p = __expf(sacc[mi][ni][r] - mnew[r]);
          psum[r] += p;
          int prow = mi * 16 + (lg << 2) + r;
          int pbyt = prow * 128 + ((((ni * 16 + l15) * 2)) ^ ((prow & 7) << 4));
          *(ushort*)((char*)Ps[w] + pbyt) = f2bf(p);
        }
#pragma unroll
      for (int msk = 1; msk < 16; msk <<= 1)
#pragma unroll
        for (int r = 0; r < 4; ++r) psum[r] += __shfl_xor(psum[r], msk, 64);
#pragma unroll
      for (int r = 0; r < 4; ++r) {
        lrun[mi][r] = lrun[mi][r] * esc[r] + psum[r];
        mrun[mi][r] = mnew[r];
      }
#pragma unroll
      for (int nd = 0; nd < 8; ++nd)
#pragma unroll
        for (int r = 0; r < 4; ++r) oacc[mi][nd][r] *= esc[r];
    }
    __syncthreads();   // P visible (and K reads done)

    // O += P V
#pragma unroll
    for (int kk2 = 0; kk2 < 2; ++kk2) {
      sv8 pf[2];
#pragma unroll
      for (int mi = 0; mi < 2; ++mi) {
        int row = mi * 16 + l15;
        int byt = row * 128 + ((kk2 * 64 + (lg << 4)) ^ ((row & 7) << 4));
        pf[mi] = *(const sv8*)((const char*)Ps[w] + byt);
      }
#pragma unroll
      for (int nd = 0; nd < 8; ++nd) {
        int row = nd * 16 + l15;
        int byt = row * 128 + ((kk2 * 64 + (lg << 4)) ^ ((row & 7) << 4));
        sv8 vf = *(const sv8*)((const char*)Vs + byt);
#pragma unroll
        for (int mi = 0; mi < 2; ++mi)
          oacc[mi][nd] = __builtin_amdgcn_mfma_f32_16x16x32_bf16(pf[mi], vf, oacc[mi][nd], 0, 0, 0);
      }
    }
    __syncthreads();   // V/P reads done before next stage
  }

  // epilogue: normalize, write (B,S,NH*HD) bf16
#pragma unroll
  for (int mi = 0; mi < 2; ++mi) {
    fv4 inv;
#pragma unroll
    for (int r = 0; r < 4; ++r) inv[r] = 1.0f / lrun[mi][r];
#pragma unroll
    for (int nd = 0; nd < 8; ++nd)
#pragma unroll
      for (int r = 0; r < 4; ++r) {
        int q = qrow_base + mi * 16 + (lg << 2) + r;
        int d = nd * 16 + l15;
        O[(size_t)(b * S_ + q) * DIM_ + h * HD + d] = f2bf(oacc[mi][nd][r] * inv[r]);
      }
  }
}

// ---------------- host launcher ----------------
extern "C" void kernel_launch(void* const* d_in, const int* in_sizes, int n_in,
                              void* d_out, int out_size, void* d_ws, size_t ws_size,
                              hipStream_t stream) {
  const float* x  = (const float*)d_in[0];
  const float* wq = (const float*)d_in[1];
  const float* wk = (const float*)d_in[2];
  const float* wv = (const float*)d_in[3];
  const float* wo = (const float*)d_in[4];
  const float* fc = (const float*)d_in[5];
  const float* fs = (const float*)d_in[6];
  float* out = (float*)d_out;

  char* ws = (char*)d_ws;
  size_t off = 0;
  auto alloc = [&](size_t bytes) -> ushort* {
    ushort* p = (ushort*)(ws + off);
    off += (bytes + 255) & ~(size_t)255;
    return p;
  };
  ushort* xb   = alloc((size_t)B_ * S_ * DIM_ * 2);        // 16MB
  ushort* wqb  = alloc((size_t)DIM_ * DIM_ * 2);           // 8MB
  ushort* wkb  = alloc((size_t)NKV * HD * DIM_ * 2);       // 2MB
  ushort* wvb  = alloc((size_t)NKV * HD * DIM_ * 2);       // 2MB
  ushort* wob  = alloc((size_t)DIM_ * DIM_ * 2);           // 8MB
  ushort* qraw = alloc((size_t)B_ * S_ * DIM_ * 2);        // 16MB
  ushort* kraw = alloc((size_t)B_ * S_ * NKV * HD * 2);    // 4MB
  ushort* vraw = alloc((size_t)B_ * S_ * NKV * HD * 2);    // 4MB
  ushort* qr   = alloc((size_t)B_ * S_ * DIM_ * 2);        // 16MB
  ushort* kr   = alloc((size_t)B_ * S_ * NKV * HD * 2);    // 4MB
  ushort* vtb  = alloc((size_t)B_ * S_ * NKV * HD * 2);    // 4MB
  ushort* obf  = alloc((size_t)B_ * S_ * DIM_ * 2);        // 16MB
  (void)ws_size; (void)n_in; (void)in_sizes; (void)out_size;

  // converts
  cvt_kernel<<<(B_ * S_ * DIM_) / 1024, 256, 0, stream>>>(x,  xb,  B_ * S_ * DIM_);
  cvt_kernel<<<(DIM_ * DIM_) / 1024,    256, 0, stream>>>(wq, wqb, DIM_ * DIM_);
  cvt_kernel<<<(NKV * HD * DIM_) / 1024,256, 0, stream>>>(wk, wkb, NKV * HD * DIM_);
  cvt_kernel<<<(NKV * HD * DIM_) / 1024,256, 0, stream>>>(wv, wvb, NKV * HD * DIM_);
  cvt_kernel<<<(DIM_ * DIM_) / 1024,    256, 0, stream>>>(wo, wob, DIM_ * DIM_);

  // projections
  gemm_bt<ushort><<<(B_ * S_ / 128) * (DIM_ / 128),     256, 0, stream>>>(xb, wqb, qraw, B_ * S_, DIM_,     DIM_);
  gemm_bt<ushort><<<(B_ * S_ / 128) * (NKV * HD / 128), 256, 0, stream>>>(xb, wkb, kraw, B_ * S_, NKV * HD, DIM_);
  gemm_bt<ushort><<<(B_ * S_ / 128) * (NKV * HD / 128), 256, 0, stream>>>(xb, wvb, vraw, B_ * S_, NKV * HD, DIM_);

  // rope + relayout (scale 1/sqrt(128) folded into Q)
  rope_kernel<<<(B_ * S_ * NH  * 16) / 256, 256, 0, stream>>>(qraw, fc, fs, qr, NH,  0.08838834764831845f);
  rope_kernel<<<(B_ * S_ * NKV * 16) / 256, 256, 0, stream>>>(kraw, fc, fs, kr, NKV, 1.0f);
  vtrans_kernel<<<B_ * NKV * (S_ / 128), 256, 0, stream>>>(vraw, vtb);

  // attention
  attn_kernel<<<B_ * NH * (S_ / 128), 256, 0, stream>>>(qr, kr, vtb, obf);

  // output projection -> f32 d_out
  gemm_bt<float><<<(B_ * S_ / 128) * (DIM_ / 128), 256, 0, stream>>>(obf, wob, out, B_ * S_, DIM_, DIM_);
}

// Round 3
// 276.416 us; speedup vs baseline: 1.4480x; 1.4480x over previous
//
#include <hip/hip_runtime.h>
#include <hip/hip_bf16.h>

// Problem constants
#define B_   2
#define S_   2048
#define DIM_ 2048
#define NH   16
#define NKV  4
#define HD   128
#define QKVN 3072   // fused projection width: 2048 (Q) + 512 (K) + 512 (V)

typedef __attribute__((ext_vector_type(8))) short  sv8;   // 8 x bf16 (MFMA operand)
typedef __attribute__((ext_vector_type(8))) ushort usv8;
typedef __attribute__((ext_vector_type(4))) float  fv4;

__device__ __forceinline__ float fast_exp2(float x) {
  return __builtin_amdgcn_exp2f(x);   // v_exp_f32 (base-2)
}

__device__ __forceinline__ ushort f2bf(float f) {
  __hip_bfloat16 h = __float2bfloat16(f);
  union { __hip_bfloat16 h; ushort u; } c; c.h = h; return c.u;
}
__device__ __forceinline__ float bf2f(ushort u) {
  union { unsigned int i; float f; } c; c.i = ((unsigned)u) << 16; return c.f;
}

// async global->LDS, 16B per lane; LDS dest must be wave-uniform (HW adds lane*16).
__device__ __forceinline__ void async16(const void* g, void* l) {
  __builtin_amdgcn_global_load_lds(
      (const __attribute__((address_space(1))) unsigned int*)g,
      (__attribute__((address_space(3))) unsigned int*)l, 16, 0, 0);
}

// ---------------- f32 -> bf16 convert ----------------
__global__ void cvt_kernel(const float* __restrict__ in, ushort* __restrict__ out, int n) {
  int i = (blockIdx.x * 256 + threadIdx.x) * 4;
  if (i >= n) return;
  fv4 v = *(const fv4*)(in + i);
  ushort4 o;
  o.x = f2bf(v[0]); o.y = f2bf(v[1]); o.z = f2bf(v[2]); o.w = f2bf(v[3]);
  *(ushort4*)(out + i) = o;
}

// ---------------- RoPE (+ scale), relayout to (B, heads, S, HD) ----------------
__global__ void rope_kernel(const ushort* __restrict__ raw, const float* __restrict__ fc,
                            const float* __restrict__ fs, ushort* __restrict__ out,
                            int heads, int rowstride, float scale) {
  int t = blockIdx.x * 256 + threadIdx.x;   // B*S*heads*16 threads, 8 elems each
  int grp = t & 15;
  int h   = (t >> 4) % heads;
  int s   = ((t >> 4) / heads) % S_;
  int b   = t / (16 * heads * S_);
  const ushort* src = raw + (size_t)(b * S_ + s) * rowstride + h * HD + grp * 8;
  sv8 v = *(const sv8*)src;
  fv4 c  = *(const fv4*)(fc + s * 64 + grp * 4);
  fv4 sn = *(const fv4*)(fs + s * 64 + grp * 4);
  sv8 o;
#pragma unroll
  for (int p = 0; p < 4; ++p) {
    float re = bf2f((ushort)v[2 * p]);
    float im = bf2f((ushort)v[2 * p + 1]);
    float orr = (re * c[p] - im * sn[p]) * scale;
    float oi  = (re * sn[p] + im * c[p]) * scale;
    o[2 * p]     = (short)f2bf(orr);
    o[2 * p + 1] = (short)f2bf(oi);
  }
  ushort* dst = out + ((size_t)(b * heads + h) * S_ + s) * HD + grp * 8;
  *(sv8*)dst = o;
}

// ---------------- V transpose: rows of fused qkv -> (B,KVH,HD,S) ----------------
__global__ __launch_bounds__(256) void vtrans_kernel(const ushort* __restrict__ vraw,
                                                     ushort* __restrict__ vt, int rowstride) {
  __shared__ ushort tile[128][136];
  int blk = blockIdx.x;            // (b*NKV+kv)*16 + st
  int st  = blk & 15;
  int kvb = blk >> 4;
  int kv  = kvb & 3;
  int b   = kvb >> 2;
  int s0  = st << 7;
#pragma unroll
  for (int it = 0; it < 8; ++it) {
    int t = it * 256 + threadIdx.x;
    int srow = t >> 4;
    int d8 = (t & 15) * 8;
    usv8 v = *(const usv8*)(vraw + (size_t)(b * S_ + s0 + srow) * rowstride + kv * HD + d8);
#pragma unroll
    for (int j = 0; j < 8; ++j) tile[d8 + j][srow] = v[j];
  }
  __syncthreads();
#pragma unroll
  for (int it = 0; it < 8; ++it) {
    int t = it * 256 + threadIdx.x;
    int d = t >> 4;
    int s8 = (t & 15) * 8;
    usv8 o;
#pragma unroll
    for (int j = 0; j < 8; ++j) o[j] = tile[d][s8 + j];
    *(usv8*)(vt + ((size_t)(b * NKV + kv) * HD + d) * S_ + s0 + s8) = o;
  }
}

// ---------------- GEMM: C[M,N] = A[M,K] * B[N,K]^T  (bf16 in, OutT out) ----------------
// 128x128 tile, BK=64, 4 waves (2x2 of 64x64), global_load_lds staging, XOR-swizzled LDS.
template <typename OutT>
__global__ __launch_bounds__(256) void gemm_bt(const ushort* __restrict__ A,
                                               const ushort* __restrict__ Bm,
                                               OutT* __restrict__ C,
                                               int M, int N, int K) {
  __shared__ ushort As[128 * 64];
  __shared__ ushort Bs[128 * 64];
  int nb = N >> 7;
  int bx = blockIdx.x % nb;
  int by = blockIdx.x / nb;
  int m0 = by << 7, n0 = bx << 7;
  int lane = threadIdx.x & 63, w = threadIdx.x >> 6;
  int l15 = lane & 15, lg = lane >> 4;
  int wm = (w >> 1) * 64, wn = (w & 1) * 64;

  const ushort* aSrc[4]; const ushort* bSrc[4];
  ushort* aDst[4]; ushort* bDst[4];
#pragma unroll
  for (int it = 0; it < 4; ++it) {
    int lin = it * 4096 + w * 1024 + lane * 16;   // byte offset into 16KB tile
    int row = lin >> 7;                           // 128B rows
    int cb  = (lin & 127) ^ ((row & 7) << 4);     // inverse swizzle on source col
    aSrc[it] = A  + (size_t)(m0 + row) * K + (cb >> 1);
    bSrc[it] = Bm + (size_t)(n0 + row) * K + (cb >> 1);
    aDst[it] = As + ((it * 4096 + w * 1024) >> 1);
    bDst[it] = Bs + ((it * 4096 + w * 1024) >> 1);
  }

  fv4 acc[4][4] = {};

  for (int kt = 0; kt < K; kt += 64) {
#pragma unroll
    for (int it = 0; it < 4; ++it) async16(aSrc[it] + kt, aDst[it]);
#pragma unroll
    for (int it = 0; it < 4; ++it) async16(bSrc[it] + kt, bDst[it]);
    __syncthreads();
#pragma unroll
    for (int kk = 0; kk < 2; ++kk) {
      sv8 af[4], bfr[4];
#pragma unroll
      for (int i = 0; i < 4; ++i) {
        int row = wm + i * 16 + l15;
        int byt = row * 128 + ((kk * 64 + (lg << 4)) ^ ((row & 7) << 4));
        af[i] = *(const sv8*)((const char*)As + byt);
      }
#pragma unroll
      for (int j = 0; j < 4; ++j) {
        int row = wn + j * 16 + l15;
        int byt = row * 128 + ((kk * 64 + (lg << 4)) ^ ((row & 7) << 4));
        bfr[j] = *(const sv8*)((const char*)Bs + byt);
      }
#pragma unroll
      for (int i = 0; i < 4; ++i)
#pragma unroll
        for (int j = 0; j < 4; ++j)
          acc[i][j] = __builtin_amdgcn_mfma_f32_16x16x32_bf16(af[i], bfr[j], acc[i][j], 0, 0, 0);
    }
    __syncthreads();
  }

#pragma unroll
  for (int i = 0; i < 4; ++i)
#pragma unroll
    for (int j = 0; j < 4; ++j)
#pragma unroll
      for (int r = 0; r < 4; ++r) {
        int row = m0 + wm + i * 16 + (lg << 2) + r;
        int col = n0 + wn + j * 16 + l15;
        if constexpr (sizeof(OutT) == 2) C[(size_t)row * N + col] = (OutT)f2bf(acc[i][j][r]);
        else                             C[(size_t)row * N + col] = (OutT)acc[i][j][r];
      }
}

// ---------------- Flash attention (causal, GQA) ----------------
// Block: 128 q-rows of one (b,h). 4 waves x 32 rows. KV tiles of 64.
// Double-buffered K/V in LDS, 1 barrier per tile, per-wave P staging.
__global__ __launch_bounds__(256) void attn_kernel(const ushort* __restrict__ Q,
                                                   const ushort* __restrict__ Kr,
                                                   const ushort* __restrict__ Vt,
                                                   ushort* __restrict__ O) {
  __shared__ ushort Ks[2][64 * 128];   // [buf][kpos][d], 256B rows, swizzled
  __shared__ ushort Vs[2][128 * 64];   // [buf][d][kpos], 128B rows, swizzled
  __shared__ ushort Ps[4][32 * 64];    // per-wave P, 128B rows, swizzled

  int blk = blockIdx.x;
  int bh  = blk & 31;                  // (b,h) fastest: spreads one q-tile depth across CUs
  int idx = blk >> 5;                  // heavy/light interleave: 15,0,14,1,...
  int qt  = (idx & 1) ? (idx >> 1) : (15 - (idx >> 1));
  int h   = bh & 15;
  int b   = bh >> 4;
  int kv  = h >> 2;
  int q0  = qt << 7;
  int lane = threadIdx.x & 63, w = threadIdx.x >> 6;
  int l15 = lane & 15, lg = lane >> 4;
  int qrow_base = q0 + w * 32;

  const ushort* Qbase = Q  + (size_t)(b * NH  + h ) * S_ * HD;
  const ushort* Kbase = Kr + (size_t)(b * NKV + kv) * S_ * HD;
  const ushort* Vbase = Vt + (size_t)(b * NKV + kv) * HD * S_;

  sv8 qf[2][4];
#pragma unroll
  for (int mi = 0; mi < 2; ++mi)
#pragma unroll
    for (int kk = 0; kk < 4; ++kk)
      qf[mi][kk] = *(const sv8*)(Qbase + (size_t)(qrow_base + mi * 16 + l15) * HD + kk * 32 + lg * 8);

  const ushort* kSrc[4]; ushort* kDst[4];
  const ushort* vSrc[4]; ushort* vDst[4];
#pragma unroll
  for (int it = 0; it < 4; ++it) {
    int lin = it * 4096 + w * 1024 + lane * 16;
    { int row = lin >> 8; int cb = (lin & 255) ^ ((row & 7) << 4);
      kSrc[it] = Kbase + (size_t)row * HD + (cb >> 1);
      kDst[it] = Ks[0] + ((it * 4096 + w * 1024) >> 1); }
    { int row = lin >> 7; int cb = (lin & 127) ^ ((row & 7) << 4);
      vSrc[it] = Vbase + (size_t)row * S_ + (cb >> 1);
      vDst[it] = Vs[0] + ((it * 4096 + w * 1024) >> 1); }
  }

  fv4 oacc[2][8] = {};
  fv4 mrun[2], lrun[2];
#pragma unroll
  for (int mi = 0; mi < 2; ++mi)
#pragma unroll
    for (int r = 0; r < 4; ++r) { mrun[mi][r] = -1e30f; lrun[mi][r] = 0.f; }

  int nkt = (q0 >> 6) + 2;

  // prologue: tile 0 into buf 0
#pragma unroll
  for (int it = 0; it < 4; ++it) async16(kSrc[it], kDst[it]);
#pragma unroll
  for (int it = 0; it < 4; ++it) async16(vSrc[it], vDst[it]);

  for (int kt = 0; kt < nkt; ++kt) {
    int cur = kt & 1, nxt = cur ^ 1;
    // Barrier: (a) drains vmcnt -> buf[cur] loads (issued one full tile ago) complete;
    // (b) all waves done reading buf[nxt] from tile kt-1 -> safe to overwrite.
    __syncthreads();
    if (kt + 1 < nkt) {
      size_t k0n = (size_t)(kt + 1) << 6;
#pragma unroll
      for (int it = 0; it < 4; ++it) async16(kSrc[it] + k0n * HD, kDst[it] + nxt * (64 * 128));
#pragma unroll
      for (int it = 0; it < 4; ++it) async16(vSrc[it] + k0n,      vDst[it] + nxt * (128 * 64));
    }
    const char* KsC = (const char*)Ks[cur];
    const char* VsC = (const char*)Vs[cur];
    int k0 = kt << 6;

    // S = Q K^T  (Q pre-scaled by log2e/sqrt(d))
    fv4 sacc[2][4] = {};
#pragma unroll
    for (int kk = 0; kk < 4; ++kk) {
#pragma unroll
      for (int ni = 0; ni < 4; ++ni) {
        int row = ni * 16 + l15;
        int byt = row * 256 + ((kk * 64 + (lg << 4)) ^ ((row & 7) << 4));
        sv8 kf = *(const sv8*)(KsC + byt);
#pragma unroll
        for (int mi = 0; mi < 2; ++mi)
          sacc[mi][ni] = __builtin_amdgcn_mfma_f32_16x16x32_bf16(qf[mi][kk], kf, sacc[mi][ni], 0, 0, 0);
      }
    }

    // causal mask on diagonal tiles
    if (k0 + 63 > q0) {
#pragma unroll
      for (int mi = 0; mi < 2; ++mi)
#pragma unroll
        for (int ni = 0; ni < 4; ++ni)
#pragma unroll
          for (int r = 0; r < 4; ++r) {
            int qrow = qrow_base + mi * 16 + (lg << 2) + r;
            int kcol = k0 + ni * 16 + l15;
            if (kcol > qrow) sacc[mi][ni][r] = -1e30f;
          }
    }

    // online softmax (base-2; scale folded into Q)
#pragma unroll
    for (int mi = 0; mi < 2; ++mi) {
      fv4 tmax = sacc[mi][0];
#pragma unroll
      for (int ni = 1; ni < 4; ++ni)
#pragma unroll
        for (int r = 0; r < 4; ++r) tmax[r] = fmaxf(tmax[r], sacc[mi][ni][r]);
#pragma unroll
      for (int msk = 1; msk < 16; msk <<= 1)
#pragma unroll
        for (int r = 0; r < 4; ++r) tmax[r] = fmaxf(tmax[r], __shfl_xor(tmax[r], msk, 64));
      fv4 mnew, esc, psum;
#pragma unroll
      for (int r = 0; r < 4; ++r) {
        mnew[r] = fmaxf(mrun[mi][r], tmax[r]);
        esc[r]  = fast_exp2(mrun[mi][r] - mnew[r]);
        psum[r] = 0.f;
      }
#pragma unroll
      for (int ni = 0; ni < 4; ++ni)
#pragma unroll
        for (int r = 0; r < 4; ++r) {
          float p = fast_exp2(sacc[mi][ni][r] - mnew[r]);
          psum[r] += p;
          int prow = mi * 16 + (lg << 2) + r;
          int pbyt = prow * 128 + ((((ni * 16 + l15) * 2)) ^ ((prow & 7) << 4));
          *(ushort*)((char*)Ps[w] + pbyt) = f2bf(p);
        }
#pragma unroll
      for (int msk = 1; msk < 16; msk <<= 1)
#pragma unroll
        for (int r = 0; r < 4; ++r) psum[r] += __shfl_xor(psum[r], msk, 64);
#pragma unroll
      for (int r = 0; r < 4; ++r) {
        lrun[mi][r] = lrun[mi][r] * esc[r] + psum[r];
        mrun[mi][r] = mnew[r];
      }
#pragma unroll
      for (int nd = 0; nd < 8; ++nd)
#pragma unroll
        for (int r = 0; r < 4; ++r) oacc[mi][nd][r] *= esc[r];
    }

    // O += P V   (Ps is per-wave: wave-internal lgkmcnt ordering suffices, no barrier)
#pragma unroll
    for (int kk2 = 0; kk2 < 2; ++kk2) {
      sv8 pf[2];
#pragma unroll
      for (int mi = 0; mi < 2; ++mi) {
        int row = mi * 16 + l15;
        int byt = row * 128 + ((kk2 * 64 + (lg << 4)) ^ ((row & 7) << 4));
        pf[mi] = *(const sv8*)((const char*)Ps[w] + byt);
      }
#pragma unroll
      for (int nd = 0; nd < 8; ++nd) {
        int row = nd * 16 + l15;
        int byt = row * 128 + ((kk2 * 64 + (lg << 4)) ^ ((row & 7) << 4));
        sv8 vf = *(const sv8*)(VsC + byt);
#pragma unroll
        for (int mi = 0; mi < 2; ++mi)
          oacc[mi][nd] = __builtin_amdgcn_mfma_f32_16x16x32_bf16(pf[mi], vf, oacc[mi][nd], 0, 0, 0);
      }
    }
  }

  // epilogue: normalize, write (B,S,NH*HD) bf16
#pragma unroll
  for (int mi = 0; mi < 2; ++mi) {
    fv4 inv;
#pragma unroll
    for (int r = 0; r < 4; ++r) inv[r] = 1.0f / lrun[mi][r];
#pragma unroll
    for (int nd = 0; nd < 8; ++nd)
#pragma unroll
      for (int r = 0; r < 4; ++r) {
        int q = qrow_base + mi * 16 + (lg << 2) + r;
        int d = nd * 16 + l15;
        O[(size_t)(b * S_ + q) * DIM_ + h * HD + d] = f2bf(oacc[mi][nd][r] * inv[r]);
      }
  }
}

// ---------------- host launcher ----------------
extern "C" void kernel_launch(void* const* d_in, const int* in_sizes, int n_in,
                              void* d_out, int out_size, void* d_ws, size_t ws_size,
                              hipStream_t stream) {
  const float* x  = (const float*)d_in[0];
  const float* wq = (const float*)d_in[1];
  const float* wk = (const float*)d_in[2];
  const float* wv = (const float*)d_in[3];
  const float* wo = (const float*)d_in[4];
  const float* fc = (const float*)d_in[5];
  const float* fs = (const float*)d_in[6];
  float* out = (float*)d_out;

  char* ws = (char*)d_ws;
  size_t off = 0;
  auto alloc = [&](size_t bytes) -> ushort* {
    ushort* p = (ushort*)(ws + off);
    off += (bytes + 255) & ~(size_t)255;
    return p;
  };
  ushort* xb    = alloc((size_t)B_ * S_ * DIM_ * 2);        // 16MB
  ushort* wqkvb = alloc((size_t)QKVN * DIM_ * 2);           // 12.6MB
  ushort* wob   = alloc((size_t)DIM_ * DIM_ * 2);           // 8MB
  ushort* qkvr  = alloc((size_t)B_ * S_ * QKVN * 2);        // 25.2MB
  ushort* qr    = alloc((size_t)B_ * S_ * DIM_ * 2);        // 16MB
  ushort* kr    = alloc((size_t)B_ * S_ * NKV * HD * 2);    // 4MB
  ushort* vtb   = alloc((size_t)B_ * S_ * NKV * HD * 2);    // 4MB
  ushort* obf   = alloc((size_t)B_ * S_ * DIM_ * 2);        // 16MB
  (void)ws_size; (void)n_in; (void)in_sizes; (void)out_size;

  // converts (weights concatenated into fused [3072][2048] buffer)
  cvt_kernel<<<(B_ * S_ * DIM_) / 1024, 256, 0, stream>>>(x,  xb, B_ * S_ * DIM_);
  cvt_kernel<<<(DIM_ * DIM_) / 1024,     256, 0, stream>>>(wq, wqkvb,                 DIM_ * DIM_);
  cvt_kernel<<<(NKV * HD * DIM_) / 1024, 256, 0, stream>>>(wk, wqkvb + 2048 * DIM_,   NKV * HD * DIM_);
  cvt_kernel<<<(NKV * HD * DIM_) / 1024, 256, 0, stream>>>(wv, wqkvb + 2560 * DIM_,   NKV * HD * DIM_);
  cvt_kernel<<<(DIM_ * DIM_) / 1024,     256, 0, stream>>>(wo, wob, DIM_ * DIM_);

  // fused QKV projection: [4096, 2048] x [3072, 2048]^T -> [4096, 3072]
  gemm_bt<ushort><<<(B_ * S_ / 128) * (QKVN / 128), 256, 0, stream>>>(xb, wqkvb, qkvr,
                                                                     B_ * S_, QKVN, DIM_);

  // rope + relayout; Q scale = 1/sqrt(128) * log2(e) (softmax runs in base 2)
  const float qscale = 0.08838834764831845f * 1.4426950408889634f;
  rope_kernel<<<(B_ * S_ * NH  * 16) / 256, 256, 0, stream>>>(qkvr,        fc, fs, qr, NH,  QKVN, qscale);
  rope_kernel<<<(B_ * S_ * NKV * 16) / 256, 256, 0, stream>>>(qkvr + 2048, fc, fs, kr, NKV, QKVN, 1.0f);
  vtrans_kernel<<<B_ * NKV * (S_ / 128), 256, 0, stream>>>(qkvr + 2560, vtb, QKVN);

  // attention
  attn_kernel<<<B_ * NH * (S_ / 128), 256, 0, stream>>>(qr, kr, vtb, obf);

  // output projection -> f32 d_out
  gemm_bt<float><<<(B_ * S_ / 128) * (DIM_ / 128), 256, 0, stream>>>(obf, wob, out, B_ * S_, DIM_, DIM_);
}

// Round 5
// 220.101 us; speedup vs baseline: 1.8185x; 1.2559x over previous
//
#include <hip/hip_runtime.h>
#include <hip/hip_bf16.h>

// Problem constants
#define B_   2
#define S_   2048
#define DIM_ 2048
#define NH   16
#define NKV  4
#define HD   128
#define QKVN 3072   // fused projection width: 2048 (Q) + 512 (K) + 512 (V)

typedef __attribute__((ext_vector_type(8)))  short  sv8;   // 8 x bf16 (MFMA operand)
typedef __attribute__((ext_vector_type(8)))  ushort usv8;
typedef __attribute__((ext_vector_type(4)))  float  fv4;
typedef __attribute__((ext_vector_type(16))) float  fv16;

__device__ __forceinline__ float fast_exp2(float x) {
  return __builtin_amdgcn_exp2f(x);   // v_exp_f32 (base-2)
}

__device__ __forceinline__ ushort f2bf(float f) {
  __hip_bfloat16 h = __float2bfloat16(f);
  union { __hip_bfloat16 h; ushort u; } c; c.h = h; return c.u;
}
__device__ __forceinline__ float bf2f(ushort u) {
  union { unsigned int i; float f; } c; c.i = ((unsigned)u) << 16; return c.f;
}

// pack two f32 -> two bf16 in one u32 (src0 -> low 16, src1 -> high 16)
__device__ __forceinline__ unsigned int cvtpk(float lo, float hi) {
  unsigned int r;
  asm("v_cvt_pk_bf16_f32 %0, %1, %2" : "=v"(r) : "v"(lo), "v"(hi));
  return r;
}
// exchange with partner lane (lane ^ 32); direction-unambiguous (ds_bpermute path)
__device__ __forceinline__ unsigned int xhalf(unsigned int x) {
  return (unsigned int)__shfl_xor((int)x, 32, 64);
}

// async global->LDS, 16B per lane; LDS dest must be wave-uniform (HW adds lane*16).
__device__ __forceinline__ void async16(const void* g, void* l) {
  __builtin_amdgcn_global_load_lds(
      (const __attribute__((address_space(1))) unsigned int*)g,
      (__attribute__((address_space(3))) unsigned int*)l, 16, 0, 0);
}

// ---------------- f32 -> bf16 convert ----------------
__global__ void cvt_kernel(const float* __restrict__ in, ushort* __restrict__ out, int n) {
  int i = (blockIdx.x * 256 + threadIdx.x) * 4;
  if (i >= n) return;
  fv4 v = *(const fv4*)(in + i);
  ushort4 o;
  o.x = f2bf(v[0]); o.y = f2bf(v[1]); o.z = f2bf(v[2]); o.w = f2bf(v[3]);
  *(ushort4*)(out + i) = o;
}

// ---------------- RoPE (+ scale), relayout to (B, heads, S, HD) ----------------
__global__ void rope_kernel(const ushort* __restrict__ raw, const float* __restrict__ fc,
                            const float* __restrict__ fs, ushort* __restrict__ out,
                            int heads, int rowstride, float scale) {
  int t = blockIdx.x * 256 + threadIdx.x;   // B*S*heads*16 threads, 8 elems each
  int grp = t & 15;
  int h   = (t >> 4) % heads;
  int s   = ((t >> 4) / heads) % S_;
  int b   = t / (16 * heads * S_);
  const ushort* src = raw + (size_t)(b * S_ + s) * rowstride + h * HD + grp * 8;
  sv8 v = *(const sv8*)src;
  fv4 c  = *(const fv4*)(fc + s * 64 + grp * 4);
  fv4 sn = *(const fv4*)(fs + s * 64 + grp * 4);
  sv8 o;
#pragma unroll
  for (int p = 0; p < 4; ++p) {
    float re = bf2f((ushort)v[2 * p]);
    float im = bf2f((ushort)v[2 * p + 1]);
    float orr = (re * c[p] - im * sn[p]) * scale;
    float oi  = (re * sn[p] + im * c[p]) * scale;
    o[2 * p]     = (short)f2bf(orr);
    o[2 * p + 1] = (short)f2bf(oi);
  }
  ushort* dst = out + ((size_t)(b * heads + h) * S_ + s) * HD + grp * 8;
  *(sv8*)dst = o;
}

// ---------------- V transpose: rows of fused qkv -> (B,KVH,HD,S) ----------------
__global__ __launch_bounds__(256) void vtrans_kernel(const ushort* __restrict__ vraw,
                                                     ushort* __restrict__ vt, int rowstride) {
  __shared__ ushort tile[128][136];
  int blk = blockIdx.x;            // (b*NKV+kv)*16 + st
  int st  = blk & 15;
  int kvb = blk >> 4;
  int kv  = kvb & 3;
  int b   = kvb >> 2;
  int s0  = st << 7;
#pragma unroll
  for (int it = 0; it < 8; ++it) {
    int t = it * 256 + threadIdx.x;
    int srow = t >> 4;
    int d8 = (t & 15) * 8;
    usv8 v = *(const usv8*)(vraw + (size_t)(b * S_ + s0 + srow) * rowstride + kv * HD + d8);
#pragma unroll
    for (int j = 0; j < 8; ++j) tile[d8 + j][srow] = v[j];
  }
  __syncthreads();
#pragma unroll
  for (int it = 0; it < 8; ++it) {
    int t = it * 256 + threadIdx.x;
    int d = t >> 4;
    int s8 = (t & 15) * 8;
    usv8 o;
#pragma unroll
    for (int j = 0; j < 8; ++j) o[j] = tile[d][s8 + j];
    *(usv8*)(vt + ((size_t)(b * NKV + kv) * HD + d) * S_ + s0 + s8) = o;
  }
}

// ---------------- GEMM: C[M,N] = A[M,K] * B[N,K]^T  (bf16 in, OutT out) ----------------
// 128x128 tile, BK=64, 4 waves (2x2 of 64x64), global_load_lds staging, XOR-swizzled LDS.
template <typename OutT>
__global__ __launch_bounds__(256) void gemm_bt(const ushort* __restrict__ A,
                                               const ushort* __restrict__ Bm,
                                               OutT* __restrict__ C,
                                               int M, int N, int K) {
  __shared__ ushort As[128 * 64];
  __shared__ ushort Bs[128 * 64];
  int nb = N >> 7;
  int bx = blockIdx.x % nb;
  int by = blockIdx.x / nb;
  int m0 = by << 7, n0 = bx << 7;
  int lane = threadIdx.x & 63, w = threadIdx.x >> 6;
  int l15 = lane & 15, lg = lane >> 4;
  int wm = (w >> 1) * 64, wn = (w & 1) * 64;

  const ushort* aSrc[4]; const ushort* bSrc[4];
  ushort* aDst[4]; ushort* bDst[4];
#pragma unroll
  for (int it = 0; it < 4; ++it) {
    int lin = it * 4096 + w * 1024 + lane * 16;   // byte offset into 16KB tile
    int row = lin >> 7;                           // 128B rows
    int cb  = (lin & 127) ^ ((row & 7) << 4);     // inverse swizzle on source col
    aSrc[it] = A  + (size_t)(m0 + row) * K + (cb >> 1);
    bSrc[it] = Bm + (size_t)(n0 + row) * K + (cb >> 1);
    aDst[it] = As + ((it * 4096 + w * 1024) >> 1);
    bDst[it] = Bs + ((it * 4096 + w * 1024) >> 1);
  }

  fv4 acc[4][4] = {};

  for (int kt = 0; kt < K; kt += 64) {
#pragma unroll
    for (int it = 0; it < 4; ++it) async16(aSrc[it] + kt, aDst[it]);
#pragma unroll
    for (int it = 0; it < 4; ++it) async16(bSrc[it] + kt, bDst[it]);
    __syncthreads();
#pragma unroll
    for (int kk = 0; kk < 2; ++kk) {
      sv8 af[4], bfr[4];
#pragma unroll
      for (int i = 0; i < 4; ++i) {
        int row = wm + i * 16 + l15;
        int byt = row * 128 + ((kk * 64 + (lg << 4)) ^ ((row & 7) << 4));
        af[i] = *(const sv8*)((const char*)As + byt);
      }
#pragma unroll
      for (int j = 0; j < 4; ++j) {
        int row = wn + j * 16 + l15;
        int byt = row * 128 + ((kk * 64 + (lg << 4)) ^ ((row & 7) << 4));
        bfr[j] = *(const sv8*)((const char*)Bs + byt);
      }
#pragma unroll
      for (int i = 0; i < 4; ++i)
#pragma unroll
        for (int j = 0; j < 4; ++j)
          acc[i][j] = __builtin_amdgcn_mfma_f32_16x16x32_bf16(af[i], bfr[j], acc[i][j], 0, 0, 0);
    }
    __syncthreads();
  }

#pragma unroll
  for (int i = 0; i < 4; ++i)
#pragma unroll
    for (int j = 0; j < 4; ++j)
#pragma unroll
      for (int r = 0; r < 4; ++r) {
        int row = m0 + wm + i * 16 + (lg << 2) + r;
        int col = n0 + wn + j * 16 + l15;
        if constexpr (sizeof(OutT) == 2) C[(size_t)row * N + col] = (OutT)f2bf(acc[i][j][r]);
        else                             C[(size_t)row * N + col] = (OutT)acc[i][j][r];
      }
}

// ---------------- Flash attention (causal, GQA) ----------------
// Block: 128 q-rows of one (b,h). 4 waves x 32 q-rows each. KV tiles of 64.
// Swapped QK^T (mfma(K, Q)) with 32x32x16: lane pair (l, l+32) holds one full
// P-row in registers -> in-register softmax (T12), no P LDS round-trip.
// Double-buffered K/V in LDS, 1 barrier per tile, defer-rescale (T13), setprio (T5).
__global__ __launch_bounds__(256, 2) void attn_kernel(const ushort* __restrict__ Q,
                                                      const ushort* __restrict__ Kr,
                                                      const ushort* __restrict__ Vt,
                                                      ushort* __restrict__ O) {
  __shared__ ushort Ks[2][64 * 128];   // [buf][kpos][d], 256B rows, swizzled
  __shared__ ushort Vs[2][128 * 64];   // [buf][d][kpos], 128B rows, swizzled

  int blk = blockIdx.x;
  int bh  = blk & 31;                  // (b,h) fastest: spreads one q-tile depth across CUs
  int idx = blk >> 5;                  // heavy/light interleave: 15,0,14,1,...
  int qt  = (idx & 1) ? (idx >> 1) : (15 - (idx >> 1));
  int h   = bh & 15;
  int b   = bh >> 4;
  int kv  = h >> 2;
  int q0  = qt << 7;
  int lane = threadIdx.x & 63, w = threadIdx.x >> 6;
  int l31 = lane & 31, hh = lane >> 5;
  int qrow_w = q0 + w * 32;            // wave's 32 q-rows
  int myq    = qrow_w + l31;           // this lane's q-row (absolute)

  const ushort* Qbase = Q  + (size_t)(b * NH  + h ) * S_ * HD;
  const ushort* Kbase = Kr + (size_t)(b * NKV + kv) * S_ * HD;
  const ushort* Vbase = Vt + (size_t)(b * NKV + kv) * HD * S_;

  // Q fragments (B-operand of 32x32x16): lane holds q-row (l&31), d = kk*16 + hh*8 .. +8
  sv8 qf[8];
#pragma unroll
  for (int kk = 0; kk < 8; ++kk)
    qf[kk] = *(const sv8*)(Qbase + (size_t)myq * HD + kk * 16 + hh * 8);

  const ushort* kSrc[4]; ushort* kDst[4];
  const ushort* vSrc[4]; ushort* vDst[4];
#pragma unroll
  for (int it = 0; it < 4; ++it) {
    int lin = it * 4096 + w * 1024 + lane * 16;
    { int row = lin >> 8; int cb = (lin & 255) ^ ((row & 7) << 4);
      kSrc[it] = Kbase + (size_t)row * HD + (cb >> 1);
      kDst[it] = Ks[0] + ((it * 4096 + w * 1024) >> 1); }
    { int row = lin >> 7; int cb = (lin & 127) ^ ((row & 7) << 4);
      vSrc[it] = Vbase + (size_t)row * S_ + (cb >> 1);
      vDst[it] = Vs[0] + ((it * 4096 + w * 1024) >> 1); }
  }

  fv16 oacc[4] = {};                   // O[q(reg-pattern), d0*32 + l31]
  float mrun = -1e30f, lrun = 0.f;     // per q-row (lane-held, dup across hh)

  int nkt = (q0 >> 6) + 2;

  // prologue: tile 0 into buf 0
#pragma unroll
  for (int it = 0; it < 4; ++it) async16(kSrc[it], kDst[it]);
#pragma unroll
  for (int it = 0; it < 4; ++it) async16(vSrc[it], vDst[it]);

  for (int kt = 0; kt < nkt; ++kt) {
    int cur = kt & 1, nxt = cur ^ 1;
    // Barrier: (a) drains vmcnt -> buf[cur] loads (issued one full tile ago) done;
    // (b) all waves finished reading buf[nxt] in tile kt-1 -> safe to overwrite.
    __syncthreads();
    if (kt + 1 < nkt) {
      size_t k0n = (size_t)(kt + 1) << 6;
#pragma unroll
      for (int it = 0; it < 4; ++it) async16(kSrc[it] + k0n * HD, kDst[it] + nxt * (64 * 128));
#pragma unroll
      for (int it = 0; it < 4; ++it) async16(vSrc[it] + k0n,      vDst[it] + nxt * (128 * 64));
    }
    const char* KsC = (const char*)Ks[cur];
    const char* VsC = (const char*)Vs[cur];
    int k0 = kt << 6;

    // S^T = K * Q^T : sacc[t] reg r <-> S[kpos = k0 + t*32 + (r&3)+8*(r>>2)+4*hh, q = myq]
    fv16 sacc[2] = {};
    __builtin_amdgcn_s_setprio(1);
#pragma unroll
    for (int kk = 0; kk < 8; ++kk) {
      int cb = kk * 32 + hh * 16;
      int r0 = l31, r1 = 32 + l31;
      sv8 kf0 = *(const sv8*)(KsC + r0 * 256 + (cb ^ ((r0 & 7) << 4)));
      sv8 kf1 = *(const sv8*)(KsC + r1 * 256 + (cb ^ ((r1 & 7) << 4)));
      sacc[0] = __builtin_amdgcn_mfma_f32_32x32x16_bf16(kf0, qf[kk], sacc[0], 0, 0, 0);
      sacc[1] = __builtin_amdgcn_mfma_f32_32x32x16_bf16(kf1, qf[kk], sacc[1], 0, 0, 0);
    }
    __builtin_amdgcn_s_setprio(0);

    // causal mask (diagonal region only)
    if (k0 + 63 > qrow_w) {
      int thr = myq - k0 - 4 * hh;
#pragma unroll
      for (int t = 0; t < 2; ++t)
#pragma unroll
        for (int r = 0; r < 16; ++r) {
          int kp = t * 32 + (r & 3) + 8 * (r >> 2);
          if (kp > thr) sacc[t][r] = -1e30f;
        }
    }

    // in-register online softmax (base-2, scale pre-folded into Q)
    float tmax = sacc[0][0];
#pragma unroll
    for (int t = 0; t < 2; ++t)
#pragma unroll
      for (int r = 0; r < 16; ++r) tmax = fmaxf(tmax, sacc[t][r]);
    tmax = fmaxf(tmax, __shfl_xor(tmax, 32, 64));   // combine hh halves -> full row max

    if (__any(tmax > mrun + 8.0f)) {   // T13: defer-rescale
      float mnew = fmaxf(mrun, tmax);
      float esc  = fast_exp2(mrun - mnew);
      lrun *= esc;
      float er[16];
#pragma unroll
      for (int r = 0; r < 16; ++r) er[r] = __shfl(esc, (r & 3) + 8 * (r >> 2) + 4 * hh, 64);
#pragma unroll
      for (int d0 = 0; d0 < 4; ++d0)
#pragma unroll
        for (int r = 0; r < 16; ++r) oacc[d0][r] *= er[r];
      mrun = mnew;
    }

    float psum = 0.f;
#pragma unroll
    for (int t = 0; t < 2; ++t)
#pragma unroll
      for (int r = 0; r < 16; ++r) {
        float p = fast_exp2(sacc[t][r] - mrun);
        sacc[t][r] = p;
        psum += p;
      }
    psum += __shfl_xor(psum, 32, 64);
    lrun += psum;

    // P -> bf16 A-fragments in-register.
    // Lane (l31,hh) holds kp = P0 + 4*hh + {0..3} (a0,a1) and P0+8+4*hh+{0..3} (b0,b1)
    // per 16-slice P0; the A-frag needs kp = P0 + 8*hh + 2*wi. Exchange halves with
    // partner lane (xhalf = shfl_xor 32) and select per hh.
    union Frag { unsigned int u[4]; sv8 v; } pa[4];
#pragma unroll
    for (int t = 0; t < 2; ++t)
#pragma unroll
      for (int half = 0; half < 2; ++half) {
        int cb = half * 8;
        unsigned int a0 = cvtpk(sacc[t][cb + 0], sacc[t][cb + 1]);
        unsigned int a1 = cvtpk(sacc[t][cb + 2], sacc[t][cb + 3]);
        unsigned int b0 = cvtpk(sacc[t][cb + 4], sacc[t][cb + 5]);
        unsigned int b1 = cvtpk(sacc[t][cb + 6], sacc[t][cb + 7]);
        unsigned int a0p = xhalf(a0), a1p = xhalf(a1);
        unsigned int b0p = xhalf(b0), b1p = xhalf(b1);
        pa[2 * t + half].u[0] = hh ? b0p : a0;
        pa[2 * t + half].u[1] = hh ? b1p : a1;
        pa[2 * t + half].u[2] = hh ? b0  : a0p;
        pa[2 * t + half].u[3] = hh ? b1  : a1p;
      }

    // O += P V : B-frag = Vs[d0*32 + l31][ks*16 + hh*8 ..]
    __builtin_amdgcn_s_setprio(1);
#pragma unroll
    for (int ks = 0; ks < 4; ++ks) {
      int cb = ks * 32 + hh * 16;
#pragma unroll
      for (int d0 = 0; d0 < 4; ++d0) {
        int row = d0 * 32 + l31;
        sv8 vf = *(const sv8*)(VsC + row * 128 + (cb ^ ((row & 7) << 4)));
        oacc[d0] = __builtin_amdgcn_mfma_f32_32x32x16_bf16(pa[ks].v, vf, oacc[d0], 0, 0, 0);
      }
    }
    __builtin_amdgcn_s_setprio(0);
  }

  // epilogue: normalize by row-sum, write (B,S,NH*HD) bf16
  float inv = 1.0f / lrun;
  float ir[16];
#pragma unroll
  for (int r = 0; r < 16; ++r) ir[r] = __shfl(inv, (r & 3) + 8 * (r >> 2) + 4 * hh, 64);
#pragma unroll
  for (int r = 0; r < 16; ++r) {
    int q = qrow_w + (r & 3) + 8 * (r >> 2) + 4 * hh;
#pragma unroll
    for (int d0 = 0; d0 < 4; ++d0) {
      int d = d0 * 32 + l31;
      O[(size_t)(b * S_ + q) * DIM_ + h * HD + d] = f2bf(oacc[d0][r] * ir[r]);
    }
  }
}

// ---------------- host launcher ----------------
extern "C" void kernel_launch(void* const* d_in, const int* in_sizes, int n_in,
                              void* d_out, int out_size, void* d_ws, size_t ws_size,
                              hipStream_t stream) {
  const float* x  = (const float*)d_in[0];
  const float* wq = (const float*)d_in[1];
  const float* wk = (const float*)d_in[2];
  const float* wv = (const float*)d_in[3];
  const float* wo = (const float*)d_in[4];
  const float* fc = (const float*)d_in[5];
  const float* fs = (const float*)d_in[6];
  float* out = (float*)d_out;

  char* ws = (char*)d_ws;
  size_t off = 0;
  auto alloc = [&](size_t bytes) -> ushort* {
    ushort* p = (ushort*)(ws + off);
    off += (bytes + 255) & ~(size_t)255;
    return p;
  };
  ushort* xb    = alloc((size_t)B_ * S_ * DIM_ * 2);        // 16MB
  ushort* wqkvb = alloc((size_t)QKVN * DIM_ * 2);           // 12.6MB
  ushort* wob   = alloc((size_t)DIM_ * DIM_ * 2);           // 8MB
  ushort* qkvr  = alloc((size_t)B_ * S_ * QKVN * 2);        // 25.2MB
  ushort* qr    = alloc((size_t)B_ * S_ * DIM_ * 2);        // 16MB
  ushort* kr    = alloc((size_t)B_ * S_ * NKV * HD * 2);    // 4MB
  ushort* vtb   = alloc((size_t)B_ * S_ * NKV * HD * 2);    // 4MB
  ushort* obf   = alloc((size_t)B_ * S_ * DIM_ * 2);        // 16MB
  (void)ws_size; (void)n_in; (void)in_sizes; (void)out_size;

  // converts (weights concatenated into fused [3072][2048] buffer)
  cvt_kernel<<<(B_ * S_ * DIM_) / 1024, 256, 0, stream>>>(x,  xb, B_ * S_ * DIM_);
  cvt_kernel<<<(DIM_ * DIM_) / 1024,     256, 0, stream>>>(wq, wqkvb,                 DIM_ * DIM_);
  cvt_kernel<<<(NKV * HD * DIM_) / 1024, 256, 0, stream>>>(wk, wqkvb + 2048 * DIM_,   NKV * HD * DIM_);
  cvt_kernel<<<(NKV * HD * DIM_) / 1024, 256, 0, stream>>>(wv, wqkvb + 2560 * DIM_,   NKV * HD * DIM_);
  cvt_kernel<<<(DIM_ * DIM_) / 1024,     256, 0, stream>>>(wo, wob, DIM_ * DIM_);

  // fused QKV projection: [4096, 2048] x [3072, 2048]^T -> [4096, 3072]
  gemm_bt<ushort><<<(B_ * S_ / 128) * (QKVN / 128), 256, 0, stream>>>(xb, wqkvb, qkvr,
                                                                     B_ * S_, QKVN, DIM_);

  // rope + relayout; Q scale = 1/sqrt(128) * log2(e) (softmax runs in base 2)
  const float qscale = 0.08838834764831845f * 1.4426950408889634f;
  rope_kernel<<<(B_ * S_ * NH  * 16) / 256, 256, 0, stream>>>(qkvr,        fc, fs, qr, NH,  QKVN, qscale);
  rope_kernel<<<(B_ * S_ * NKV * 16) / 256, 256, 0, stream>>>(qkvr + 2048, fc, fs, kr, NKV, QKVN, 1.0f);
  vtrans_kernel<<<B_ * NKV * (S_ / 128), 256, 0, stream>>>(qkvr + 2560, vtb, QKVN);

  // attention
  attn_kernel<<<B_ * NH * (S_ / 128), 256, 0, stream>>>(qr, kr, vtb, obf);

  // output projection -> f32 d_out
  gemm_bt<float><<<(B_ * S_ / 128) * (DIM_ / 128), 256, 0, stream>>>(obf, wob, out, B_ * S_, DIM_, DIM_);
}

// Round 6
// 216.664 us; speedup vs baseline: 1.8474x; 1.0159x over previous
//
#include <hip/hip_runtime.h>
#include <hip/hip_bf16.h>

// Problem constants
#define B_   2
#define S_   2048
#define DIM_ 2048
#define NH   16
#define NKV  4
#define HD   128
#define QKVN 3072   // fused projection width: 2048 (Q) + 512 (K) + 512 (V)

typedef __attribute__((ext_vector_type(8)))  short  sv8;   // 8 x bf16 (MFMA operand)
typedef __attribute__((ext_vector_type(8)))  ushort usv8;
typedef __attribute__((ext_vector_type(4)))  float  fv4;
typedef __attribute__((ext_vector_type(16))) float  fv16;

__device__ __forceinline__ float fast_exp2(float x) {
  return __builtin_amdgcn_exp2f(x);   // v_exp_f32 (base-2)
}

__device__ __forceinline__ ushort f2bf(float f) {
  __hip_bfloat16 h = __float2bfloat16(f);
  union { __hip_bfloat16 h; ushort u; } c; c.h = h; return c.u;
}
__device__ __forceinline__ float bf2f(ushort u) {
  union { unsigned int i; float f; } c; c.i = ((unsigned)u) << 16; return c.f;
}

// pack two f32 -> two bf16 in one u32 (src0 -> low 16, src1 -> high 16)
__device__ __forceinline__ unsigned int cvtpk(float lo, float hi) {
  unsigned int r;
  asm("v_cvt_pk_bf16_f32 %0, %1, %2" : "=v"(r) : "v"(lo), "v"(hi));
  return r;
}
// exchange with partner lane (lane ^ 32)
__device__ __forceinline__ unsigned int xhalf(unsigned int x) {
  return (unsigned int)__shfl_xor((int)x, 32, 64);
}

// tree reductions over a 16-vector (depth 5, ILP-friendly)
__device__ __forceinline__ float tmax16(const fv16& v) {
  float a = fmaxf(fmaxf(v[0], v[1]),  fmaxf(v[2], v[3]));
  float b = fmaxf(fmaxf(v[4], v[5]),  fmaxf(v[6], v[7]));
  float c = fmaxf(fmaxf(v[8], v[9]),  fmaxf(v[10], v[11]));
  float d = fmaxf(fmaxf(v[12], v[13]), fmaxf(v[14], v[15]));
  return fmaxf(fmaxf(a, b), fmaxf(c, d));
}
__device__ __forceinline__ float tsum16(const fv16& v) {
  float a = (v[0] + v[1]) + (v[2] + v[3]);
  float b = (v[4] + v[5]) + (v[6] + v[7]);
  float c = (v[8] + v[9]) + (v[10] + v[11]);
  float d = (v[12] + v[13]) + (v[14] + v[15]);
  return (a + b) + (c + d);
}

// async global->LDS, 16B per lane; LDS dest must be wave-uniform (HW adds lane*16).
__device__ __forceinline__ void async16(const void* g, void* l) {
  __builtin_amdgcn_global_load_lds(
      (const __attribute__((address_space(1))) unsigned int*)g,
      (__attribute__((address_space(3))) unsigned int*)l, 16, 0, 0);
}

// ---------------- f32 -> bf16 convert ----------------
__global__ void cvt_kernel(const float* __restrict__ in, ushort* __restrict__ out, int n) {
  int i = (blockIdx.x * 256 + threadIdx.x) * 4;
  if (i >= n) return;
  fv4 v = *(const fv4*)(in + i);
  ushort4 o;
  o.x = f2bf(v[0]); o.y = f2bf(v[1]); o.z = f2bf(v[2]); o.w = f2bf(v[3]);
  *(ushort4*)(out + i) = o;
}

// ---------------- RoPE (+ scale), relayout to (B, heads, S, HD) ----------------
__global__ void rope_kernel(const ushort* __restrict__ raw, const float* __restrict__ fc,
                            const float* __restrict__ fs, ushort* __restrict__ out,
                            int heads, int rowstride, float scale) {
  int t = blockIdx.x * 256 + threadIdx.x;   // B*S*heads*16 threads, 8 elems each
  int grp = t & 15;
  int h   = (t >> 4) % heads;
  int s   = ((t >> 4) / heads) % S_;
  int b   = t / (16 * heads * S_);
  const ushort* src = raw + (size_t)(b * S_ + s) * rowstride + h * HD + grp * 8;
  sv8 v = *(const sv8*)src;
  fv4 c  = *(const fv4*)(fc + s * 64 + grp * 4);
  fv4 sn = *(const fv4*)(fs + s * 64 + grp * 4);
  sv8 o;
#pragma unroll
  for (int p = 0; p < 4; ++p) {
    float re = bf2f((ushort)v[2 * p]);
    float im = bf2f((ushort)v[2 * p + 1]);
    float orr = (re * c[p] - im * sn[p]) * scale;
    float oi  = (re * sn[p] + im * c[p]) * scale;
    o[2 * p]     = (short)f2bf(orr);
    o[2 * p + 1] = (short)f2bf(oi);
  }
  ushort* dst = out + ((size_t)(b * heads + h) * S_ + s) * HD + grp * 8;
  *(sv8*)dst = o;
}

// ---------------- V transpose: rows of fused qkv -> (B,KVH,HD,S) ----------------
__global__ __launch_bounds__(256) void vtrans_kernel(const ushort* __restrict__ vraw,
                                                     ushort* __restrict__ vt, int rowstride) {
  __shared__ ushort tile[128][136];
  int blk = blockIdx.x;            // (b*NKV+kv)*16 + st
  int st  = blk & 15;
  int kvb = blk >> 4;
  int kv  = kvb & 3;
  int b   = kvb >> 2;
  int s0  = st << 7;
#pragma unroll
  for (int it = 0; it < 8; ++it) {
    int t = it * 256 + threadIdx.x;
    int srow = t >> 4;
    int d8 = (t & 15) * 8;
    usv8 v = *(const usv8*)(vraw + (size_t)(b * S_ + s0 + srow) * rowstride + kv * HD + d8);
#pragma unroll
    for (int j = 0; j < 8; ++j) tile[d8 + j][srow] = v[j];
  }
  __syncthreads();
#pragma unroll
  for (int it = 0; it < 8; ++it) {
    int t = it * 256 + threadIdx.x;
    int d = t >> 4;
    int s8 = (t & 15) * 8;
    usv8 o;
#pragma unroll
    for (int j = 0; j < 8; ++j) o[j] = tile[d][s8 + j];
    *(usv8*)(vt + ((size_t)(b * NKV + kv) * HD + d) * S_ + s0 + s8) = o;
  }
}

// ---------------- GEMM: C[M,N] = A[M,K] * B[N,K]^T  (bf16 in, OutT out) ----------------
// 128x128 tile, BK=64, 4 waves (2x2 of 64x64), global_load_lds staging, XOR-swizzled LDS.
template <typename OutT>
__global__ __launch_bounds__(256) void gemm_bt(const ushort* __restrict__ A,
                                               const ushort* __restrict__ Bm,
                                               OutT* __restrict__ C,
                                               int M, int N, int K) {
  __shared__ ushort As[128 * 64];
  __shared__ ushort Bs[128 * 64];
  int nb = N >> 7;
  int bx = blockIdx.x % nb;
  int by = blockIdx.x / nb;
  int m0 = by << 7, n0 = bx << 7;
  int lane = threadIdx.x & 63, w = threadIdx.x >> 6;
  int l15 = lane & 15, lg = lane >> 4;
  int wm = (w >> 1) * 64, wn = (w & 1) * 64;

  const ushort* aSrc[4]; const ushort* bSrc[4];
  ushort* aDst[4]; ushort* bDst[4];
#pragma unroll
  for (int it = 0; it < 4; ++it) {
    int lin = it * 4096 + w * 1024 + lane * 16;   // byte offset into 16KB tile
    int row = lin >> 7;                           // 128B rows
    int cb  = (lin & 127) ^ ((row & 7) << 4);     // inverse swizzle on source col
    aSrc[it] = A  + (size_t)(m0 + row) * K + (cb >> 1);
    bSrc[it] = Bm + (size_t)(n0 + row) * K + (cb >> 1);
    aDst[it] = As + ((it * 4096 + w * 1024) >> 1);
    bDst[it] = Bs + ((it * 4096 + w * 1024) >> 1);
  }

  fv4 acc[4][4] = {};

  for (int kt = 0; kt < K; kt += 64) {
#pragma unroll
    for (int it = 0; it < 4; ++it) async16(aSrc[it] + kt, aDst[it]);
#pragma unroll
    for (int it = 0; it < 4; ++it) async16(bSrc[it] + kt, bDst[it]);
    __syncthreads();
#pragma unroll
    for (int kk = 0; kk < 2; ++kk) {
      sv8 af[4], bfr[4];
#pragma unroll
      for (int i = 0; i < 4; ++i) {
        int row = wm + i * 16 + l15;
        int byt = row * 128 + ((kk * 64 + (lg << 4)) ^ ((row & 7) << 4));
        af[i] = *(const sv8*)((const char*)As + byt);
      }
#pragma unroll
      for (int j = 0; j < 4; ++j) {
        int row = wn + j * 16 + l15;
        int byt = row * 128 + ((kk * 64 + (lg << 4)) ^ ((row & 7) << 4));
        bfr[j] = *(const sv8*)((const char*)Bs + byt);
      }
#pragma unroll
      for (int i = 0; i < 4; ++i)
#pragma unroll
        for (int j = 0; j < 4; ++j)
          acc[i][j] = __builtin_amdgcn_mfma_f32_16x16x32_bf16(af[i], bfr[j], acc[i][j], 0, 0, 0);
    }
    __syncthreads();
  }

#pragma unroll
  for (int i = 0; i < 4; ++i)
#pragma unroll
    for (int j = 0; j < 4; ++j)
#pragma unroll
      for (int r = 0; r < 4; ++r) {
        int row = m0 + wm + i * 16 + (lg << 2) + r;
        int col = n0 + wn + j * 16 + l15;
        if constexpr (sizeof(OutT) == 2) C[(size_t)row * N + col] = (OutT)f2bf(acc[i][j][r]);
        else                             C[(size_t)row * N + col] = (OutT)acc[i][j][r];
      }
}

// ---------------- Flash attention (causal, GQA) ----------------
// Block: TWO complementary 128-row q-tiles (qt, 15-qt) of one (b,h) -> every
// block does exactly 36 KV tiles (static load balance; grid = 256 = 1/CU).
// 4 waves x 32 q-rows. Swapped QK^T (mfma(K,Q), 32x32x16): lane pair (l,l+32)
// holds a full P-row -> in-register softmax (T12). Double-buffered K/V LDS,
// 1 barrier/tile, defer-rescale (T13), setprio (T5), tree reductions.
__global__ __launch_bounds__(256, 2) void attn_kernel(const ushort* __restrict__ Q,
                                                      const ushort* __restrict__ Kr,
                                                      const ushort* __restrict__ Vt,
                                                      ushort* __restrict__ O) {
  __shared__ ushort Ks[2][64 * 128];   // [buf][kpos][d], 256B rows, swizzled
  __shared__ ushort Vs[2][128 * 64];   // [buf][d][kpos], 128B rows, swizzled

  int blk = blockIdx.x;
  int bh  = blk & 31;                  // (b,h) fastest: spreads K/V reuse across XCDs
  int pr  = blk >> 5;                  // 0..7: q-tile pair (pr, 15-pr)
  int h   = bh & 15;
  int b   = bh >> 4;
  int kv  = h >> 2;
  int lane = threadIdx.x & 63, w = threadIdx.x >> 6;
  int l31 = lane & 31, hh = lane >> 5;

  const ushort* Qbase = Q  + (size_t)(b * NH  + h ) * S_ * HD;
  const ushort* Kbase = Kr + (size_t)(b * NKV + kv) * S_ * HD;
  const ushort* Vbase = Vt + (size_t)(b * NKV + kv) * HD * S_;

  // staging pointers (q-tile independent)
  const ushort* kSrc[4]; ushort* kDst[4];
  const ushort* vSrc[4]; ushort* vDst[4];
#pragma unroll
  for (int it = 0; it < 4; ++it) {
    int lin = it * 4096 + w * 1024 + lane * 16;
    { int row = lin >> 8; int cb = (lin & 255) ^ ((row & 7) << 4);
      kSrc[it] = Kbase + (size_t)row * HD + (cb >> 1);
      kDst[it] = Ks[0] + ((it * 4096 + w * 1024) >> 1); }
    { int row = lin >> 7; int cb = (lin & 127) ^ ((row & 7) << 4);
      vSrc[it] = Vbase + (size_t)row * S_ + (cb >> 1);
      vDst[it] = Vs[0] + ((it * 4096 + w * 1024) >> 1); }
  }

  for (int pass = 0; pass < 2; ++pass) {
    int qt = pass ? (15 - pr) : pr;
    int q0 = qt << 7;
    int qrow_w = q0 + w * 32;          // wave's 32 q-rows
    int myq    = qrow_w + l31;         // this lane's q-row (absolute)

    // Q fragments (B-operand of 32x32x16): lane holds q-row (l&31), d = kk*16+hh*8..
    sv8 qf[8];
#pragma unroll
    for (int kk = 0; kk < 8; ++kk)
      qf[kk] = *(const sv8*)(Qbase + (size_t)myq * HD + kk * 16 + hh * 8);

    fv16 oacc[4] = {};                 // O[q(reg-pattern), d0*32 + l31]
    float mrun = -1e30f, lrun = 0.f;   // per q-row (lane-held, dup across hh)

    int nkt = (q0 >> 6) + 2;           // even

    // Pass isolation: all waves must finish pass-0 LDS reads before buf0 rewrite.
    if (pass) __syncthreads();

    // prologue: tile 0 into buf 0
#pragma unroll
    for (int it = 0; it < 4; ++it) async16(kSrc[it], kDst[it]);
#pragma unroll
    for (int it = 0; it < 4; ++it) async16(vSrc[it], vDst[it]);

    for (int kt = 0; kt < nkt; ++kt) {
      int cur = kt & 1, nxt = cur ^ 1;
      // Barrier: (a) drains vmcnt -> buf[cur] loads (issued one tile ago) done;
      // (b) all waves finished reading buf[nxt] in tile kt-1 -> safe to overwrite.
      __syncthreads();
      if (kt + 1 < nkt) {
        size_t k0n = (size_t)(kt + 1) << 6;
#pragma unroll
        for (int it = 0; it < 4; ++it) async16(kSrc[it] + k0n * HD, kDst[it] + nxt * (64 * 128));
#pragma unroll
        for (int it = 0; it < 4; ++it) async16(vSrc[it] + k0n,      vDst[it] + nxt * (128 * 64));
      }
      const char* KsC = (const char*)Ks[cur];
      const char* VsC = (const char*)Vs[cur];
      int k0 = kt << 6;

      // S^T = K * Q^T : sacc[t] reg r <-> S[kpos = k0+t*32+(r&3)+8*(r>>2)+4*hh, q=myq]
      fv16 sacc[2] = {};
      __builtin_amdgcn_s_setprio(1);
#pragma unroll
      for (int kk = 0; kk < 8; ++kk) {
        int cb = kk * 32 + hh * 16;
        int r0 = l31, r1 = 32 + l31;
        sv8 kf0 = *(const sv8*)(KsC + r0 * 256 + (cb ^ ((r0 & 7) << 4)));
        sv8 kf1 = *(const sv8*)(KsC + r1 * 256 + (cb ^ ((r1 & 7) << 4)));
        sacc[0] = __builtin_amdgcn_mfma_f32_32x32x16_bf16(kf0, qf[kk], sacc[0], 0, 0, 0);
        sacc[1] = __builtin_amdgcn_mfma_f32_32x32x16_bf16(kf1, qf[kk], sacc[1], 0, 0, 0);
      }
      __builtin_amdgcn_s_setprio(0);

      // causal mask (diagonal region only)
      if (k0 + 63 > qrow_w) {
        int thr = myq - k0 - 4 * hh;
#pragma unroll
        for (int t = 0; t < 2; ++t)
#pragma unroll
          for (int r = 0; r < 16; ++r) {
            int kp = t * 32 + (r & 3) + 8 * (r >> 2);
            if (kp > thr) sacc[t][r] = -1e30f;
          }
      }

      // in-register online softmax (base-2; scale pre-folded into Q); tree reduce
      float tmax = fmaxf(tmax16(sacc[0]), tmax16(sacc[1]));
      tmax = fmaxf(tmax, __shfl_xor(tmax, 32, 64));   // combine hh halves

      if (__any(tmax > mrun + 8.0f)) {   // T13: defer-rescale
        float mnew = fmaxf(mrun, tmax);
        float esc  = fast_exp2(mrun - mnew);
        lrun *= esc;
        float er[16];
#pragma unroll
        for (int r = 0; r < 16; ++r) er[r] = __shfl(esc, (r & 3) + 8 * (r >> 2) + 4 * hh, 64);
#pragma unroll
        for (int d0 = 0; d0 < 4; ++d0)
#pragma unroll
          for (int r = 0; r < 16; ++r) oacc[d0][r] *= er[r];
        mrun = mnew;
      }

#pragma unroll
      for (int t = 0; t < 2; ++t)
#pragma unroll
        for (int r = 0; r < 16; ++r) sacc[t][r] = fast_exp2(sacc[t][r] - mrun);
      float psum = tsum16(sacc[0]) + tsum16(sacc[1]);
      psum += __shfl_xor(psum, 32, 64);
      lrun += psum;

      // P -> bf16 A-fragments in-register (cvt_pk + half-exchange).
      union Frag { unsigned int u[4]; sv8 v; } pa[4];
#pragma unroll
      for (int t = 0; t < 2; ++t)
#pragma unroll
        for (int half = 0; half < 2; ++half) {
          int cb = half * 8;
          unsigned int a0 = cvtpk(sacc[t][cb + 0], sacc[t][cb + 1]);
          unsigned int a1 = cvtpk(sacc[t][cb + 2], sacc[t][cb + 3]);
          unsigned int b0 = cvtpk(sacc[t][cb + 4], sacc[t][cb + 5]);
          unsigned int b1 = cvtpk(sacc[t][cb + 6], sacc[t][cb + 7]);
          unsigned int a0p = xhalf(a0), a1p = xhalf(a1);
          unsigned int b0p = xhalf(b0), b1p = xhalf(b1);
          pa[2 * t + half].u[0] = hh ? b0p : a0;
          pa[2 * t + half].u[1] = hh ? b1p : a1;
          pa[2 * t + half].u[2] = hh ? b0  : a0p;
          pa[2 * t + half].u[3] = hh ? b1  : a1p;
        }

      // O += P V : B-frag = Vs[d0*32 + l31][ks*16 + hh*8 ..]
      __builtin_amdgcn_s_setprio(1);
#pragma unroll
      for (int ks = 0; ks < 4; ++ks) {
        int cb = ks * 32 + hh * 16;
#pragma unroll
        for (int d0 = 0; d0 < 4; ++d0) {
          int row = d0 * 32 + l31;
          sv8 vf = *(const sv8*)(VsC + row * 128 + (cb ^ ((row & 7) << 4)));
          oacc[d0] = __builtin_amdgcn_mfma_f32_32x32x16_bf16(pa[ks].v, vf, oacc[d0], 0, 0, 0);
        }
      }
      __builtin_amdgcn_s_setprio(0);
    }

    // epilogue: normalize by row-sum, write (B,S,NH*HD) bf16
    float inv = 1.0f / lrun;
    float ir[16];
#pragma unroll
    for (int r = 0; r < 16; ++r) ir[r] = __shfl(inv, (r & 3) + 8 * (r >> 2) + 4 * hh, 64);
#pragma unroll
    for (int r = 0; r < 16; ++r) {
      int q = qrow_w + (r & 3) + 8 * (r >> 2) + 4 * hh;
#pragma unroll
      for (int d0 = 0; d0 < 4; ++d0) {
        int d = d0 * 32 + l31;
        O[(size_t)(b * S_ + q) * DIM_ + h * HD + d] = f2bf(oacc[d0][r] * ir[r]);
      }
    }
  }
}

// ---------------- host launcher ----------------
extern "C" void kernel_launch(void* const* d_in, const int* in_sizes, int n_in,
                              void* d_out, int out_size, void* d_ws, size_t ws_size,
                              hipStream_t stream) {
  const float* x  = (const float*)d_in[0];
  const float* wq = (const float*)d_in[1];
  const float* wk = (const float*)d_in[2];
  const float* wv = (const float*)d_in[3];
  const float* wo = (const float*)d_in[4];
  const float* fc = (const float*)d_in[5];
  const float* fs = (const float*)d_in[6];
  float* out = (float*)d_out;

  char* ws = (char*)d_ws;
  size_t off = 0;
  auto alloc = [&](size_t bytes) -> ushort* {
    ushort* p = (ushort*)(ws + off);
    off += (bytes + 255) & ~(size_t)255;
    return p;
  };
  ushort* xb    = alloc((size_t)B_ * S_ * DIM_ * 2);        // 16MB
  ushort* wqkvb = alloc((size_t)QKVN * DIM_ * 2);           // 12.6MB
  ushort* wob   = alloc((size_t)DIM_ * DIM_ * 2);           // 8MB
  ushort* qkvr  = alloc((size_t)B_ * S_ * QKVN * 2);        // 25.2MB
  ushort* qr    = alloc((size_t)B_ * S_ * DIM_ * 2);        // 16MB
  ushort* kr    = alloc((size_t)B_ * S_ * NKV * HD * 2);    // 4MB
  ushort* vtb   = alloc((size_t)B_ * S_ * NKV * HD * 2);    // 4MB
  ushort* obf   = alloc((size_t)B_ * S_ * DIM_ * 2);        // 16MB
  (void)ws_size; (void)n_in; (void)in_sizes; (void)out_size;

  // converts (weights concatenated into fused [3072][2048] buffer)
  cvt_kernel<<<(B_ * S_ * DIM_) / 1024, 256, 0, stream>>>(x,  xb, B_ * S_ * DIM_);
  cvt_kernel<<<(DIM_ * DIM_) / 1024,     256, 0, stream>>>(wq, wqkvb,                 DIM_ * DIM_);
  cvt_kernel<<<(NKV * HD * DIM_) / 1024, 256, 0, stream>>>(wk, wqkvb + 2048 * DIM_,   NKV * HD * DIM_);
  cvt_kernel<<<(NKV * HD * DIM_) / 1024, 256, 0, stream>>>(wv, wqkvb + 2560 * DIM_,   NKV * HD * DIM_);
  cvt_kernel<<<(DIM_ * DIM_) / 1024,     256, 0, stream>>>(wo, wob, DIM_ * DIM_);

  // fused QKV projection: [4096, 2048] x [3072, 2048]^T -> [4096, 3072]
  gemm_bt<ushort><<<(B_ * S_ / 128) * (QKVN / 128), 256, 0, stream>>>(xb, wqkvb, qkvr,
                                                                     B_ * S_, QKVN, DIM_);

  // rope + relayout; Q scale = 1/sqrt(128) * log2(e) (softmax runs in base 2)
  const float qscale = 0.08838834764831845f * 1.4426950408889634f;
  rope_kernel<<<(B_ * S_ * NH  * 16) / 256, 256, 0, stream>>>(qkvr,        fc, fs, qr, NH,  QKVN, qscale);
  rope_kernel<<<(B_ * S_ * NKV * 16) / 256, 256, 0, stream>>>(qkvr + 2048, fc, fs, kr, NKV, QKVN, 1.0f);
  vtrans_kernel<<<B_ * NKV * (S_ / 128), 256, 0, stream>>>(qkvr + 2560, vtb, QKVN);

  // attention: 256 blocks, each does q-tile pair (pr, 15-pr) = uniform 36 KV tiles
  attn_kernel<<<B_ * NH * 8, 256, 0, stream>>>(qr, kr, vtb, obf);

  // output projection -> f32 d_out
  gemm_bt<float><<<(B_ * S_ / 128) * (DIM_ / 128), 256, 0, stream>>>(obf, wob, out, B_ * S_, DIM_, DIM_);
}

// Round 7
// 201.461 us; speedup vs baseline: 1.9868x; 1.0755x over previous
//
#include <hip/hip_runtime.h>
#include <hip/hip_bf16.h>

// Problem constants
#define B_   2
#define S_   2048
#define DIM_ 2048
#define NH   16
#define NKV  4
#define HD   128
#define QKVN 3072   // fused projection width: 2048 (Q) + 512 (K) + 512 (V)

typedef __attribute__((ext_vector_type(8)))  short  sv8;   // 8 x bf16 (MFMA operand)
typedef __attribute__((ext_vector_type(8)))  ushort usv8;
typedef __attribute__((ext_vector_type(4)))  float  fv4;
typedef __attribute__((ext_vector_type(16))) float  fv16;

__device__ __forceinline__ float fast_exp2(float x) {
  return __builtin_amdgcn_exp2f(x);   // v_exp_f32 (base-2)
}

__device__ __forceinline__ ushort f2bf(float f) {
  __hip_bfloat16 h = __float2bfloat16(f);
  union { __hip_bfloat16 h; ushort u; } c; c.h = h; return c.u;
}
__device__ __forceinline__ float bf2f(ushort u) {
  union { unsigned int i; float f; } c; c.i = ((unsigned)u) << 16; return c.f;
}

// pack two f32 -> two bf16 in one u32 (src0 -> low 16, src1 -> high 16)
__device__ __forceinline__ unsigned int cvtpk(float lo, float hi) {
  unsigned int r;
  asm("v_cvt_pk_bf16_f32 %0, %1, %2" : "=v"(r) : "v"(lo), "v"(hi));
  return r;
}
// exchange with partner lane (lane ^ 32)
__device__ __forceinline__ unsigned int xhalf(unsigned int x) {
  return (unsigned int)__shfl_xor((int)x, 32, 64);
}

// tree reductions over a 16-vector (depth 5, ILP-friendly)
__device__ __forceinline__ float tmax16(const fv16& v) {
  float a = fmaxf(fmaxf(v[0], v[1]),  fmaxf(v[2], v[3]));
  float b = fmaxf(fmaxf(v[4], v[5]),  fmaxf(v[6], v[7]));
  float c = fmaxf(fmaxf(v[8], v[9]),  fmaxf(v[10], v[11]));
  float d = fmaxf(fmaxf(v[12], v[13]), fmaxf(v[14], v[15]));
  return fmaxf(fmaxf(a, b), fmaxf(c, d));
}
__device__ __forceinline__ float tsum16(const fv16& v) {
  float a = (v[0] + v[1]) + (v[2] + v[3]);
  float b = (v[4] + v[5]) + (v[6] + v[7]);
  float c = (v[8] + v[9]) + (v[10] + v[11]);
  float d = (v[12] + v[13]) + (v[14] + v[15]);
  return (a + b) + (c + d);
}

// async global->LDS, 16B per lane; LDS dest must be wave-uniform (HW adds lane*16).
__device__ __forceinline__ void async16(const void* g, void* l) {
  __builtin_amdgcn_global_load_lds(
      (const __attribute__((address_space(1))) unsigned int*)g,
      (__attribute__((address_space(3))) unsigned int*)l, 16, 0, 0);
}

// ---------------- f32 -> bf16 convert ----------------
__global__ void cvt_kernel(const float* __restrict__ in, ushort* __restrict__ out, int n) {
  int i = (blockIdx.x * 256 + threadIdx.x) * 4;
  if (i >= n) return;
  fv4 v = *(const fv4*)(in + i);
  ushort4 o;
  o.x = f2bf(v[0]); o.y = f2bf(v[1]); o.z = f2bf(v[2]); o.w = f2bf(v[3]);
  *(ushort4*)(out + i) = o;
}

// ---------------- RoPE (+ scale), relayout to (B, heads, S, HD) ----------------
__global__ void rope_kernel(const ushort* __restrict__ raw, const float* __restrict__ fc,
                            const float* __restrict__ fs, ushort* __restrict__ out,
                            int heads, int rowstride, float scale) {
  int t = blockIdx.x * 256 + threadIdx.x;   // B*S*heads*16 threads, 8 elems each
  int grp = t & 15;
  int h   = (t >> 4) % heads;
  int s   = ((t >> 4) / heads) % S_;
  int b   = t / (16 * heads * S_);
  const ushort* src = raw + (size_t)(b * S_ + s) * rowstride + h * HD + grp * 8;
  sv8 v = *(const sv8*)src;
  fv4 c  = *(const fv4*)(fc + s * 64 + grp * 4);
  fv4 sn = *(const fv4*)(fs + s * 64 + grp * 4);
  sv8 o;
#pragma unroll
  for (int p = 0; p < 4; ++p) {
    float re = bf2f((ushort)v[2 * p]);
    float im = bf2f((ushort)v[2 * p + 1]);
    float orr = (re * c[p] - im * sn[p]) * scale;
    float oi  = (re * sn[p] + im * c[p]) * scale;
    o[2 * p]     = (short)f2bf(orr);
    o[2 * p + 1] = (short)f2bf(oi);
  }
  ushort* dst = out + ((size_t)(b * heads + h) * S_ + s) * HD + grp * 8;
  *(sv8*)dst = o;
}

// ---------------- V transpose: rows of fused qkv -> (B,KVH,HD,S) ----------------
__global__ __launch_bounds__(256) void vtrans_kernel(const ushort* __restrict__ vraw,
                                                     ushort* __restrict__ vt, int rowstride) {
  __shared__ ushort tile[128][136];
  int blk = blockIdx.x;            // (b*NKV+kv)*16 + st
  int st  = blk & 15;
  int kvb = blk >> 4;
  int kv  = kvb & 3;
  int b   = kvb >> 2;
  int s0  = st << 7;
#pragma unroll
  for (int it = 0; it < 8; ++it) {
    int t = it * 256 + threadIdx.x;
    int srow = t >> 4;
    int d8 = (t & 15) * 8;
    usv8 v = *(const usv8*)(vraw + (size_t)(b * S_ + s0 + srow) * rowstride + kv * HD + d8);
#pragma unroll
    for (int j = 0; j < 8; ++j) tile[d8 + j][srow] = v[j];
  }
  __syncthreads();
#pragma unroll
  for (int it = 0; it < 8; ++it) {
    int t = it * 256 + threadIdx.x;
    int d = t >> 4;
    int s8 = (t & 15) * 8;
    usv8 o;
#pragma unroll
    for (int j = 0; j < 8; ++j) o[j] = tile[d][s8 + j];
    *(usv8*)(vt + ((size_t)(b * NKV + kv) * HD + d) * S_ + s0 + s8) = o;
  }
}

// ---------------- GEMM: C[M,N] = A[M,K] * B[N,K]^T  (bf16 in, OutT out) ----------------
// 128x128 tile, BK=64, 4 waves (2x2 of 64x64), global_load_lds staging, XOR-swizzled LDS.
template <typename OutT>
__global__ __launch_bounds__(256) void gemm_bt(const ushort* __restrict__ A,
                                               const ushort* __restrict__ Bm,
                                               OutT* __restrict__ C,
                                               int M, int N, int K) {
  __shared__ ushort As[128 * 64];
  __shared__ ushort Bs[128 * 64];
  int nb = N >> 7;
  int bx = blockIdx.x % nb;
  int by = blockIdx.x / nb;
  int m0 = by << 7, n0 = bx << 7;
  int lane = threadIdx.x & 63, w = threadIdx.x >> 6;
  int l15 = lane & 15, lg = lane >> 4;
  int wm = (w >> 1) * 64, wn = (w & 1) * 64;

  const ushort* aSrc[4]; const ushort* bSrc[4];
  ushort* aDst[4]; ushort* bDst[4];
#pragma unroll
  for (int it = 0; it < 4; ++it) {
    int lin = it * 4096 + w * 1024 + lane * 16;   // byte offset into 16KB tile
    int row = lin >> 7;                           // 128B rows
    int cb  = (lin & 127) ^ ((row & 7) << 4);     // inverse swizzle on source col
    aSrc[it] = A  + (size_t)(m0 + row) * K + (cb >> 1);
    bSrc[it] = Bm + (size_t)(n0 + row) * K + (cb >> 1);
    aDst[it] = As + ((it * 4096 + w * 1024) >> 1);
    bDst[it] = Bs + ((it * 4096 + w * 1024) >> 1);
  }

  fv4 acc[4][4] = {};

  for (int kt = 0; kt < K; kt += 64) {
#pragma unroll
    for (int it = 0; it < 4; ++it) async16(aSrc[it] + kt, aDst[it]);
#pragma unroll
    for (int it = 0; it < 4; ++it) async16(bSrc[it] + kt, bDst[it]);
    __syncthreads();
#pragma unroll
    for (int kk = 0; kk < 2; ++kk) {
      sv8 af[4], bfr[4];
#pragma unroll
      for (int i = 0; i < 4; ++i) {
        int row = wm + i * 16 + l15;
        int byt = row * 128 + ((kk * 64 + (lg << 4)) ^ ((row & 7) << 4));
        af[i] = *(const sv8*)((const char*)As + byt);
      }
#pragma unroll
      for (int j = 0; j < 4; ++j) {
        int row = wn + j * 16 + l15;
        int byt = row * 128 + ((kk * 64 + (lg << 4)) ^ ((row & 7) << 4));
        bfr[j] = *(const sv8*)((const char*)Bs + byt);
      }
#pragma unroll
      for (int i = 0; i < 4; ++i)
#pragma unroll
        for (int j = 0; j < 4; ++j)
          acc[i][j] = __builtin_amdgcn_mfma_f32_16x16x32_bf16(af[i], bfr[j], acc[i][j], 0, 0, 0);
    }
    __syncthreads();
  }

#pragma unroll
  for (int i = 0; i < 4; ++i)
#pragma unroll
    for (int j = 0; j < 4; ++j)
#pragma unroll
      for (int r = 0; r < 4; ++r) {
        int row = m0 + wm + i * 16 + (lg << 2) + r;
        int col = n0 + wn + j * 16 + l15;
        if constexpr (sizeof(OutT) == 2) C[(size_t)row * N + col] = (OutT)f2bf(acc[i][j][r]);
        else                             C[(size_t)row * N + col] = (OutT)acc[i][j][r];
      }
}

// ---------------- Flash attention (causal, GQA) ----------------
// Block: 512 thr = 8 waves. Two complementary q-tiles (pr, 15-pr), two passes.
// Per pass: waves 0-3 (low half) process k-tiles [0,nj), waves 4-7 (high half)
// [nj,2nj) of the SAME 128 q-rows (nj = qt+1) -> serial chain per wave = 17
// tiles uniform. Each half has private double-buffered K/V LDS (128KB total).
// Partials (m,l,O) merged through LDS once per pass. Swapped QK^T 32x32x16,
// in-register softmax (T12), defer-rescale (T13), setprio (T5).
// MASKVAL=-1e38 < m_init=-1e30 so fully-masked tiles give p=exp2(-1e38-m)=0.
__global__ __launch_bounds__(512, 2) void attn_kernel(const ushort* __restrict__ Q,
                                                      const ushort* __restrict__ Kr,
                                                      const ushort* __restrict__ Vt,
                                                      ushort* __restrict__ O) {
  __shared__ __align__(16) ushort SMEM[65536];   // 128KB
  // layout (ushort units): K: [half][buf][8192] at Hf*16384+buf*8192
  //                        V: 32768 + [half][buf][8192]
  // combine region (floats, aliased; guarded by barriers):
  //   cML: [g*64+lane]*2 at float offset 0 (2KB)
  //   cO : [(g*64+lane)*65 + idx] at float offset 512 (65KB, stride 65 anti-conflict)

  int blk = blockIdx.x;
  int bh  = blk & 31;                  // (b,h) fastest: spreads K/V reuse across XCDs
  int pr  = blk >> 5;                  // 0..7: q-tile pair (pr, 15-pr)
  int h   = bh & 15;
  int b   = bh >> 4;
  int kv  = h >> 2;
  int lane = threadIdx.x & 63, w = threadIdx.x >> 6;
  int wg = w & 3, Hf = w >> 2;         // row-group, k-half
  int l31 = lane & 31, hh = lane >> 5;

  const ushort* Qbase = Q  + (size_t)(b * NH  + h ) * S_ * HD;
  const ushort* Kbase = Kr + (size_t)(b * NKV + kv) * S_ * HD;
  const ushort* Vbase = Vt + (size_t)(b * NKV + kv) * HD * S_;

  // staging pointers (q-tile independent; per-half LDS dest)
  const ushort* kSrc[4]; ushort* kDst[2][4];
  const ushort* vSrc[4]; ushort* vDst[2][4];
#pragma unroll
  for (int it = 0; it < 4; ++it) {
    int lin = it * 4096 + wg * 1024 + lane * 16;
    { int row = lin >> 8; int cb = (lin & 255) ^ ((row & 7) << 4);
      kSrc[it] = Kbase + (size_t)row * HD + (cb >> 1); }
    { int row = lin >> 7; int cb = (lin & 127) ^ ((row & 7) << 4);
      vSrc[it] = Vbase + (size_t)row * S_ + (cb >> 1); }
#pragma unroll
    for (int buf = 0; buf < 2; ++buf) {
      kDst[buf][it] = SMEM + Hf * 16384 + buf * 8192 + ((it * 4096 + wg * 1024) >> 1);
      vDst[buf][it] = SMEM + 32768 + Hf * 16384 + buf * 8192 + ((it * 4096 + wg * 1024) >> 1);
    }
  }

  float* cML = (float*)SMEM;
  float* cO  = (float*)SMEM + 512;

  for (int pass = 0; pass < 2; ++pass) {
    int qt = pass ? (15 - pr) : pr;
    int q0 = qt << 7;
    int qrow_w = q0 + wg * 32;         // wave's 32 q-rows
    int myq    = qrow_w + l31;         // this lane's q-row (absolute)
    int nj     = qt + 1;               // k-tiles per half
    int ktbase = Hf * nj;              // this half's first k-tile

    // Q fragments (B-operand of 32x32x16): lane holds q-row (l&31), d = kk*16+hh*8..
    sv8 qf[8];
#pragma unroll
    for (int kk = 0; kk < 8; ++kk)
      qf[kk] = *(const sv8*)(Qbase + (size_t)myq * HD + kk * 16 + hh * 8);

    fv16 oacc[4] = {};                 // O[q(reg-pattern), d0*32 + l31]
    float mrun = -1e30f, lrun = 0.f;   // per q-row (lane-held, dup across hh)

    // prologue: this half's tile 0 into buf 0
    {
      size_t k0 = (size_t)ktbase << 6;
#pragma unroll
      for (int it = 0; it < 4; ++it) async16(kSrc[it] + k0 * HD, kDst[0][it]);
#pragma unroll
      for (int it = 0; it < 4; ++it) async16(vSrc[it] + k0,      vDst[0][it]);
    }

    for (int j = 0; j < nj; ++j) {
      int cur = j & 1, nxt = cur ^ 1;
      // Barrier: drains vmcnt -> buf[cur] loads done; all waves done with buf[nxt].
      __syncthreads();
      if (j + 1 < nj) {
        size_t k0n = (size_t)(ktbase + j + 1) << 6;
#pragma unroll
        for (int it = 0; it < 4; ++it) async16(kSrc[it] + k0n * HD, kDst[nxt][it]);
#pragma unroll
        for (int it = 0; it < 4; ++it) async16(vSrc[it] + k0n,      vDst[nxt][it]);
      }
      const char* KsC = (const char*)(SMEM + Hf * 16384 + cur * 8192);
      const char* VsC = (const char*)(SMEM + 32768 + Hf * 16384 + cur * 8192);
      int k0 = (ktbase + j) << 6;

      // S^T = K * Q^T : sacc[t] reg r <-> S[kpos = k0+t*32+(r&3)+8*(r>>2)+4*hh, q=myq]
      fv16 sacc[2] = {};
      __builtin_amdgcn_s_setprio(1);
#pragma unroll
      for (int kk = 0; kk < 8; ++kk) {
        int cb = kk * 32 + hh * 16;
        int r0 = l31, r1 = 32 + l31;
        sv8 kf0 = *(const sv8*)(KsC + r0 * 256 + (cb ^ ((r0 & 7) << 4)));
        sv8 kf1 = *(const sv8*)(KsC + r1 * 256 + (cb ^ ((r1 & 7) << 4)));
        sacc[0] = __builtin_amdgcn_mfma_f32_32x32x16_bf16(kf0, qf[kk], sacc[0], 0, 0, 0);
        sacc[1] = __builtin_amdgcn_mfma_f32_32x32x16_bf16(kf1, qf[kk], sacc[1], 0, 0, 0);
      }
      __builtin_amdgcn_s_setprio(0);

      // causal mask (MASKVAL far below m_init so all-masked tiles are safe)
      if (k0 + 63 > qrow_w) {
        int thr = myq - k0 - 4 * hh;
#pragma unroll
        for (int t = 0; t < 2; ++t)
#pragma unroll
          for (int r = 0; r < 16; ++r) {
            int kp = t * 32 + (r & 3) + 8 * (r >> 2);
            if (kp > thr) sacc[t][r] = -1e38f;
          }
      }

      // in-register online softmax (base-2; scale pre-folded into Q); tree reduce
      float tmax = fmaxf(tmax16(sacc[0]), tmax16(sacc[1]));
      tmax = fmaxf(tmax, __shfl_xor(tmax, 32, 64));   // combine hh halves

      if (__any(tmax > mrun + 8.0f)) {   // T13: defer-rescale
        float mnew = fmaxf(mrun, tmax);
        float esc  = fast_exp2(mrun - mnew);
        lrun *= esc;
        float er[16];
#pragma unroll
        for (int r = 0; r < 16; ++r) er[r] = __shfl(esc, (r & 3) + 8 * (r >> 2) + 4 * hh, 64);
#pragma unroll
        for (int d0 = 0; d0 < 4; ++d0)
#pragma unroll
          for (int r = 0; r < 16; ++r) oacc[d0][r] *= er[r];
        mrun = mnew;
      }

#pragma unroll
      for (int t = 0; t < 2; ++t)
#pragma unroll
        for (int r = 0; r < 16; ++r) sacc[t][r] = fast_exp2(sacc[t][r] - mrun);
      float psum = tsum16(sacc[0]) + tsum16(sacc[1]);
      psum += __shfl_xor(psum, 32, 64);
      lrun += psum;

      // P -> bf16 A-fragments in-register (cvt_pk + half-exchange).
      union Frag { unsigned int u[4]; sv8 v; } pa[4];
#pragma unroll
      for (int t = 0; t < 2; ++t)
#pragma unroll
        for (int half = 0; half < 2; ++half) {
          int cb = half * 8;
          unsigned int a0 = cvtpk(sacc[t][cb + 0], sacc[t][cb + 1]);
          unsigned int a1 = cvtpk(sacc[t][cb + 2], sacc[t][cb + 3]);
          unsigned int b0 = cvtpk(sacc[t][cb + 4], sacc[t][cb + 5]);
          unsigned int b1 = cvtpk(sacc[t][cb + 6], sacc[t][cb + 7]);
          unsigned int a0p = xhalf(a0), a1p = xhalf(a1);
          unsigned int b0p = xhalf(b0), b1p = xhalf(b1);
          pa[2 * t + half].u[0] = hh ? b0p : a0;
          pa[2 * t + half].u[1] = hh ? b1p : a1;
          pa[2 * t + half].u[2] = hh ? b0  : a0p;
          pa[2 * t + half].u[3] = hh ? b1  : a1p;
        }

      // O += P V : B-frag = Vs[d0*32 + l31][ks*16 + hh*8 ..]
      __builtin_amdgcn_s_setprio(1);
#pragma unroll
      for (int ks = 0; ks < 4; ++ks) {
        int cb = ks * 32 + hh * 16;
#pragma unroll
        for (int d0 = 0; d0 < 4; ++d0) {
          int row = d0 * 32 + l31;
          sv8 vf = *(const sv8*)(VsC + row * 128 + (cb ^ ((row & 7) << 4)));
          oacc[d0] = __builtin_amdgcn_mfma_f32_32x32x16_bf16(pa[ks].v, vf, oacc[d0], 0, 0, 0);
        }
      }
      __builtin_amdgcn_s_setprio(0);
    }

    // ---- combine halves (low = waves 0-3 merges; high = waves 4-7 deposits) ----
    __syncthreads();                       // bar1: all staging reads done; SMEM reusable
    if (Hf) {
      int base = wg * 64 + lane;
      cML[base * 2]     = mrun;
      cML[base * 2 + 1] = lrun;
      float* dst = cO + base * 65;
#pragma unroll
      for (int d0 = 0; d0 < 4; ++d0)
#pragma unroll
        for (int r = 0; r < 16; ++r) dst[d0 * 16 + r] = oacc[d0][r];
    }
    __syncthreads();                       // bar2: deposits visible
    if (!Hf) {
      int base = wg * 64 + lane;
      float m2 = cML[base * 2], l2 = cML[base * 2 + 1];
      const float* src = cO + base * 65;
      float m  = fmaxf(mrun, m2);
      float e1 = fast_exp2(mrun - m), e2 = fast_exp2(m2 - m);
      float l  = lrun * e1 + l2 * e2;
      float inv = 1.0f / l;
      float f1 = e1 * inv, f2 = e2 * inv;
      float f1b[16], f2b[16];
#pragma unroll
      for (int r = 0; r < 16; ++r) {
        int ro = (r & 3) + 8 * (r >> 2) + 4 * hh;
        f1b[r] = __shfl(f1, ro, 64);
        f2b[r] = __shfl(f2, ro, 64);
      }
#pragma unroll
      for (int r = 0; r < 16; ++r) {
        int q = qrow_w + (r & 3) + 8 * (r >> 2) + 4 * hh;
#pragma unroll
        for (int d0 = 0; d0 < 4; ++d0) {
          int d = d0 * 32 + l31;
          float val = oacc[d0][r] * f1b[r] + src[d0 * 16 + r] * f2b[r];
          O[(size_t)(b * S_ + q) * DIM_ + h * HD + d] = f2bf(val);
        }
      }
    }
    __syncthreads();                       // bar3: combine reads done before next prologue
  }
}

// ---------------- host launcher ----------------
extern "C" void kernel_launch(void* const* d_in, const int* in_sizes, int n_in,
                              void* d_out, int out_size, void* d_ws, size_t ws_size,
                              hipStream_t stream) {
  const float* x  = (const float*)d_in[0];
  const float* wq = (const float*)d_in[1];
  const float* wk = (const float*)d_in[2];
  const float* wv = (const float*)d_in[3];
  const float* wo = (const float*)d_in[4];
  const float* fc = (const float*)d_in[5];
  const float* fs = (const float*)d_in[6];
  float* out = (float*)d_out;

  char* ws = (char*)d_ws;
  size_t off = 0;
  auto alloc = [&](size_t bytes) -> ushort* {
    ushort* p = (ushort*)(ws + off);
    off += (bytes + 255) & ~(size_t)255;
    return p;
  };
  ushort* xb    = alloc((size_t)B_ * S_ * DIM_ * 2);        // 16MB
  ushort* wqkvb = alloc((size_t)QKVN * DIM_ * 2);           // 12.6MB
  ushort* wob   = alloc((size_t)DIM_ * DIM_ * 2);           // 8MB
  ushort* qkvr  = alloc((size_t)B_ * S_ * QKVN * 2);        // 25.2MB
  ushort* qr    = alloc((size_t)B_ * S_ * DIM_ * 2);        // 16MB
  ushort* kr    = alloc((size_t)B_ * S_ * NKV * HD * 2);    // 4MB
  ushort* vtb   = alloc((size_t)B_ * S_ * NKV * HD * 2);    // 4MB
  ushort* obf   = alloc((size_t)B_ * S_ * DIM_ * 2);        // 16MB
  (void)ws_size; (void)n_in; (void)in_sizes; (void)out_size;

  // converts (weights concatenated into fused [3072][2048] buffer)
  cvt_kernel<<<(B_ * S_ * DIM_) / 1024, 256, 0, stream>>>(x,  xb, B_ * S_ * DIM_);
  cvt_kernel<<<(DIM_ * DIM_) / 1024,     256, 0, stream>>>(wq, wqkvb,                 DIM_ * DIM_);
  cvt_kernel<<<(NKV * HD * DIM_) / 1024, 256, 0, stream>>>(wk, wqkvb + 2048 * DIM_,   NKV * HD * DIM_);
  cvt_kernel<<<(NKV * HD * DIM_) / 1024, 256, 0, stream>>>(wv, wqkvb + 2560 * DIM_,   NKV * HD * DIM_);
  cvt_kernel<<<(DIM_ * DIM_) / 1024,     256, 0, stream>>>(wo, wob, DIM_ * DIM_);

  // fused QKV projection: [4096, 2048] x [3072, 2048]^T -> [4096, 3072]
  gemm_bt<ushort><<<(B_ * S_ / 128) * (QKVN / 128), 256, 0, stream>>>(xb, wqkvb, qkvr,
                                                                     B_ * S_, QKVN, DIM_);

  // rope + relayout; Q scale = 1/sqrt(128) * log2(e) (softmax runs in base 2)
  const float qscale = 0.08838834764831845f * 1.4426950408889634f;
  rope_kernel<<<(B_ * S_ * NH  * 16) / 256, 256, 0, stream>>>(qkvr,        fc, fs, qr, NH,  QKVN, qscale);
  rope_kernel<<<(B_ * S_ * NKV * 16) / 256, 256, 0, stream>>>(qkvr + 2048, fc, fs, kr, NKV, QKVN, 1.0f);
  vtrans_kernel<<<B_ * NKV * (S_ / 128), 256, 0, stream>>>(qkvr + 2560, vtb, QKVN);

  // attention: 256 blocks x 512 thr; uniform 17-tile chains per wave (k-split + pair)
  attn_kernel<<<B_ * NH * 8, 512, 0, stream>>>(qr, kr, vtb, obf);

  // output projection -> f32 d_out
  gemm_bt<float><<<(B_ * S_ / 128) * (DIM_ / 128), 256, 0, stream>>>(obf, wob, out, B_ * S_, DIM_, DIM_);
}